// Round 1
// baseline (5941.099 us; speedup 1.0000x reference)
//
#include <hip/hip_runtime.h>
#include <math.h>

#define NN 50000
#define NE 600000
#define ADIM 75
#define HID 128
#define NLAYERS 4
#define NGRAPHS 128
#define BN_EPS 1e-5f
#define TN 16   // nodes per block in tiled node kernels

__device__ __forceinline__ float sigm(float v) { return 1.0f / (1.0f + __expf(-v)); }

// ---------------------------------------------------------------------------
// Embedding: y = relu(nf @ embW^T + embb), accumulate BN sums (double atomics)
// block 256 = 16 nodes x 16 f-groups; grid 3125
// ---------------------------------------------------------------------------
__global__ __launch_bounds__(256) void k_embed(
    const float* __restrict__ nf, const float* __restrict__ W,
    const float* __restrict__ b, float* __restrict__ y,
    double* __restrict__ bnsum)
{
    __shared__ float sNF[TN * 80];     // 75 padded to 80
    __shared__ float sW[128 * 76];     // 75 padded to 76
    __shared__ float sH[TN * 128];
    const int t = threadIdx.x;
    const int node0 = blockIdx.x * TN;

    for (int i = t; i < TN * ADIM; i += 256) {
        int r = i / ADIM, c = i - r * ADIM;
        sNF[r * 80 + c] = nf[node0 * ADIM + i];
    }
    for (int i = t; i < 128 * ADIM; i += 256) {
        int r = i / ADIM, c = i - r * ADIM;
        sW[r * 76 + c] = W[i];
    }
    __syncthreads();

    const int node = t >> 4, fg = t & 15;
    float acc[8];
#pragma unroll
    for (int j = 0; j < 8; j++) acc[j] = b[fg + 16 * j];

    const float* arow = &sNF[node * 80];
#pragma unroll 6
    for (int k = 0; k < 72; k += 4) {
        float4 a = *(const float4*)&arow[k];
#pragma unroll
        for (int j = 0; j < 8; j++) {
            float4 w = *(const float4*)&sW[(fg + 16 * j) * 76 + k];
            acc[j] += a.x * w.x + a.y * w.y + a.z * w.z + a.w * w.w;
        }
    }
    for (int k = 72; k < 75; k++) {
        float a = arow[k];
#pragma unroll
        for (int j = 0; j < 8; j++) acc[j] += a * sW[(fg + 16 * j) * 76 + k];
    }
#pragma unroll
    for (int j = 0; j < 8; j++) {
        float v = fmaxf(acc[j], 0.0f);
        int f = fg + 16 * j;
        sH[node * 128 + f] = v;
        y[(node0 + node) * HID + f] = v;
    }
    __syncthreads();
    if (t < 128) {
        float s = 0.f, s2 = 0.f;
#pragma unroll
        for (int n2 = 0; n2 < TN; n2++) { float v = sH[n2 * 128 + t]; s += v; s2 += v * v; }
        unsafeAtomicAdd(&bnsum[t], (double)s);
        unsafeAtomicAdd(&bnsum[128 + t], (double)s2);
    }
}

// ---------------------------------------------------------------------------
// BN finalize: scale/shift from double sums
// ---------------------------------------------------------------------------
__global__ void k_bnfin(const double* __restrict__ bnsum, const float* __restrict__ g,
                        const float* __restrict__ beta, float* __restrict__ ss)
{
    int f = threadIdx.x;
    double mean = bnsum[f] / (double)NN;
    double var  = bnsum[128 + f] / (double)NN - mean * mean;
    float inv = rsqrtf((float)var + BN_EPS);
    float sc = g[f] * inv;
    ss[f] = sc;
    ss[128 + f] = beta[f] - (float)mean * sc;
}

// ---------------------------------------------------------------------------
// BN apply: x = y*scale + shift   (float4 elementwise, grid 6250)
// ---------------------------------------------------------------------------
__global__ __launch_bounds__(256) void k_bnapply(
    const float* __restrict__ y, const float* __restrict__ ss, float* __restrict__ x)
{
    int i = blockIdx.x * 256 + threadIdx.x;      // float4 index
    int f = (i * 4) & 127;
    float4 v = ((const float4*)y)[i];
    float4 sc = *(const float4*)&ss[f];
    float4 sh = *(const float4*)&ss[128 + f];
    float4 r;
    r.x = v.x * sc.x + sh.x; r.y = v.y * sc.y + sh.y;
    r.z = v.z * sc.z + sh.z; r.w = v.w * sc.w + sh.w;
    ((float4*)x)[i] = r;
}

// ---------------------------------------------------------------------------
// Node pre: m = x @ msgW^T + msgb ; a_s = x . attW[:128] ; a_d = x . attW[128:]
// block 256 = 16 nodes x 16 f-groups; grid 3125
// ---------------------------------------------------------------------------
__global__ __launch_bounds__(256) void k_node_pre(
    const float* __restrict__ x, const float* __restrict__ Wm,
    const float* __restrict__ bm, const float* __restrict__ attW,
    float* __restrict__ m, float* __restrict__ as_, float* __restrict__ ad_)
{
    __shared__ float sX[TN * 132];
    __shared__ float sW[64 * 132];
    const int t = threadIdx.x;
    const int node0 = blockIdx.x * TN;
    {
        const float4* src = (const float4*)(x + (size_t)node0 * HID);
#pragma unroll
        for (int i = 0; i < 2; i++) {
            int f4 = t + i * 256;
            float4 v = src[f4];
            int r = f4 >> 5, c = (f4 & 31) * 4;
            *(float4*)&sX[r * 132 + c] = v;
        }
    }
    __syncthreads();
    const int node = t >> 4, fg = t & 15;

    // attention projections
    float pas = 0.f, pad = 0.f;
#pragma unroll
    for (int j = 0; j < 8; j++) {
        int f = fg + 16 * j;
        float xv = sX[node * 132 + f];
        pas += xv * attW[f];
        pad += xv * attW[128 + f];
    }
#pragma unroll
    for (int msk = 8; msk >= 1; msk >>= 1) {
        pas += __shfl_xor(pas, msk);
        pad += __shfl_xor(pad, msk);
    }
    if (fg == 0) { as_[node0 + node] = pas; ad_[node0 + node] = pad; }

    float acc[8];
#pragma unroll
    for (int j = 0; j < 8; j++) acc[j] = bm[fg + 16 * j];

#pragma unroll
    for (int pass = 0; pass < 2; pass++) {
        __syncthreads();
        const float4* wsrc = (const float4*)(Wm + pass * 64 * HID);
#pragma unroll
        for (int i = 0; i < 8; i++) {
            int f4 = t + i * 256;
            float4 v = wsrc[f4];
            int r = f4 >> 5, c = (f4 & 31) * 4;
            *(float4*)&sW[r * 132 + c] = v;
        }
        __syncthreads();
        const float* arow = &sX[node * 132];
        float t0 = 0.f, t1 = 0.f, t2 = 0.f, t3 = 0.f;
#pragma unroll 4
        for (int k = 0; k < 128; k += 4) {
            float4 a = *(const float4*)&arow[k];
            float4 w0 = *(const float4*)&sW[(fg +  0) * 132 + k];
            float4 w1 = *(const float4*)&sW[(fg + 16) * 132 + k];
            float4 w2 = *(const float4*)&sW[(fg + 32) * 132 + k];
            float4 w3 = *(const float4*)&sW[(fg + 48) * 132 + k];
            t0 += a.x * w0.x + a.y * w0.y + a.z * w0.z + a.w * w0.w;
            t1 += a.x * w1.x + a.y * w1.y + a.z * w1.z + a.w * w1.w;
            t2 += a.x * w2.x + a.y * w2.y + a.z * w2.z + a.w * w2.w;
            t3 += a.x * w3.x + a.y * w3.y + a.z * w3.z + a.w * w3.w;
        }
        acc[pass * 4 + 0] += t0; acc[pass * 4 + 1] += t1;
        acc[pass * 4 + 2] += t2; acc[pass * 4 + 3] += t3;
    }
#pragma unroll
    for (int j = 0; j < 8; j++)
        m[(node0 + node) * HID + fg + 16 * j] = acc[j];
}

// ---------------------------------------------------------------------------
// Edge scatter: agg[dst] += m[src] * sigmoid(a_s[src] + a_d[dst] + attb)
// block 256 = 8 edges x 32 lanes (float4 per lane); grid 75000
// ---------------------------------------------------------------------------
__global__ __launch_bounds__(256) void k_edge(
    const int* __restrict__ src, const int* __restrict__ dst,
    const float* __restrict__ m, const float* __restrict__ as_,
    const float* __restrict__ ad_, const float* __restrict__ attb, int l,
    float* __restrict__ agg)
{
    const int t = threadIdx.x;
    const int e = blockIdx.x * 8 + (t >> 5);
    const int lane = t & 31;
    const int s = src[e], d = dst[e];
    const float att = sigm(as_[s] + ad_[d] + attb[l]);
    float4 v = *(const float4*)&m[(size_t)s * HID + lane * 4];
    float* p = &agg[(size_t)d * HID + lane * 4];
    unsafeAtomicAdd(p + 0, v.x * att);
    unsafeAtomicAdd(p + 1, v.y * att);
    unsafeAtomicAdd(p + 2, v.z * att);
    unsafeAtomicAdd(p + 3, v.w * att);
}

// ---------------------------------------------------------------------------
// Fused GRU: gi = agg@Wih^T+bih, gh = x@Whh^T+bhh, gates, h_new, BN sums
// block 256 = 16 nodes x 16 f-groups; grid 3125
// 12 weight-chunk passes (6 for Wih, 6 for Whh), 64 rows x 128 K each in LDS
// ---------------------------------------------------------------------------
__global__ __launch_bounds__(256) void k_gru(
    const float* __restrict__ agg, const float* __restrict__ x,
    const float* __restrict__ Wih, const float* __restrict__ bih,
    const float* __restrict__ Whh, const float* __restrict__ bhh,
    float* __restrict__ y, double* __restrict__ bnsum)
{
    __shared__ float sA[TN * 132];
    __shared__ float sX[TN * 132];
    __shared__ float sW[64 * 132];
    __shared__ float sH[TN * 128];
    const int t = threadIdx.x;
    const int node0 = blockIdx.x * TN;
    {
        const float4* sa = (const float4*)(agg + (size_t)node0 * HID);
        const float4* sx = (const float4*)(x + (size_t)node0 * HID);
#pragma unroll
        for (int i = 0; i < 2; i++) {
            int f4 = t + i * 256;
            int r = f4 >> 5, c = (f4 & 31) * 4;
            *(float4*)&sA[r * 132 + c] = sa[f4];
            *(float4*)&sX[r * 132 + c] = sx[f4];
        }
    }
    const int node = t >> 4, fg = t & 15;

    float acci[24], acch[24];
#pragma unroll
    for (int gj = 0; gj < 24; gj++) {
        int gate = gj >> 3, j = gj & 7;
        acci[gj] = bih[gate * 128 + fg + 16 * j];
        acch[gj] = bhh[gate * 128 + fg + 16 * j];
    }

#pragma unroll
    for (int pass = 0; pass < 12; pass++) {
        __syncthreads();
        const int pm = (pass < 6) ? pass : (pass - 6);
        const float4* wsrc = (const float4*)(((pass < 6) ? Wih : Whh) + pm * 64 * HID);
#pragma unroll
        for (int i = 0; i < 8; i++) {
            int f4 = t + i * 256;
            int r = f4 >> 5, c = (f4 & 31) * 4;
            *(float4*)&sW[r * 132 + c] = wsrc[f4];
        }
        __syncthreads();
        const float* arow = (pass < 6) ? &sA[node * 132] : &sX[node * 132];
        float t0 = 0.f, t1 = 0.f, t2 = 0.f, t3 = 0.f;
#pragma unroll 4
        for (int k = 0; k < 128; k += 4) {
            float4 a = *(const float4*)&arow[k];
            float4 w0 = *(const float4*)&sW[(fg +  0) * 132 + k];
            float4 w1 = *(const float4*)&sW[(fg + 16) * 132 + k];
            float4 w2 = *(const float4*)&sW[(fg + 32) * 132 + k];
            float4 w3 = *(const float4*)&sW[(fg + 48) * 132 + k];
            t0 += a.x * w0.x + a.y * w0.y + a.z * w0.z + a.w * w0.w;
            t1 += a.x * w1.x + a.y * w1.y + a.z * w1.z + a.w * w1.w;
            t2 += a.x * w2.x + a.y * w2.y + a.z * w2.z + a.w * w2.w;
            t3 += a.x * w3.x + a.y * w3.y + a.z * w3.z + a.w * w3.w;
        }
        float* acc = (pass < 6) ? acci : acch;   // folded: pass is compile-time
        const int base = pm * 4;                 // = gate*8 + fhalf*4
        acc[base + 0] += t0; acc[base + 1] += t1;
        acc[base + 2] += t2; acc[base + 3] += t3;
    }

#pragma unroll
    for (int j = 0; j < 8; j++) {
        int f = fg + 16 * j;
        float r = sigm(acci[j] + acch[j]);
        float z = sigm(acci[8 + j] + acch[8 + j]);
        float n = tanhf(acci[16 + j] + r * acch[16 + j]);
        float xv = sX[node * 132 + f];
        float h = (1.0f - z) * n + z * xv;
        sH[node * 128 + f] = h;
        y[(node0 + node) * HID + f] = h;
    }
    __syncthreads();
    if (t < 128) {
        float s = 0.f, s2 = 0.f;
#pragma unroll
        for (int n2 = 0; n2 < TN; n2++) { float v = sH[n2 * 128 + t]; s += v; s2 += v * v; }
        unsafeAtomicAdd(&bnsum[t], (double)s);
        unsafeAtomicAdd(&bnsum[128 + t], (double)s2);
    }
}

// ---------------------------------------------------------------------------
// Graph sum-pool: gr[batch[n]] += x[n]    block 256 = 8 nodes x 32 lanes
// ---------------------------------------------------------------------------
__global__ __launch_bounds__(256) void k_pool(
    const float* __restrict__ x, const int* __restrict__ batch, float* __restrict__ gr)
{
    const int t = threadIdx.x;
    const int n = blockIdx.x * 8 + (t >> 5);
    const int lane = t & 31;
    const int g = batch[n];
    float4 v = *(const float4*)&x[(size_t)n * HID + lane * 4];
    float* p = &gr[(size_t)g * HID + lane * 4];
    unsafeAtomicAdd(p + 0, v.x);
    unsafeAtomicAdd(p + 1, v.y);
    unsafeAtomicAdd(p + 2, v.z);
    unsafeAtomicAdd(p + 3, v.w);
}

// ---------------------------------------------------------------------------
// Readout: out[g] = relu(gr[g] @ W1^T + b1) @ W2^T + b2   (128 blocks x 64)
// ---------------------------------------------------------------------------
__global__ __launch_bounds__(64) void k_readout(
    const float* __restrict__ gr, const float* __restrict__ W1,
    const float* __restrict__ b1, const float* __restrict__ W2,
    const float* __restrict__ b2, float* __restrict__ out)
{
    const int g = blockIdx.x, j = threadIdx.x;
    float acc = b1[j];
    const float4* grow = (const float4*)&gr[g * HID];
    const float4* wrow = (const float4*)&W1[j * HID];
#pragma unroll
    for (int k4 = 0; k4 < 32; k4++) {
        float4 a = grow[k4], w = wrow[k4];
        acc += a.x * w.x + a.y * w.y + a.z * w.z + a.w * w.w;
    }
    float h = fmaxf(acc, 0.0f) * W2[j];
#pragma unroll
    for (int msk = 32; msk >= 1; msk >>= 1) h += __shfl_xor(h, msk);
    if (j == 0) out[g] = h + b2[0];
}

// ---------------------------------------------------------------------------
extern "C" void kernel_launch(void* const* d_in, const int* in_sizes, int n_in,
                              void* d_out, int out_size, void* d_ws, size_t ws_size,
                              hipStream_t stream)
{
    const float* nf    = (const float*)d_in[0];
    const int*   ei    = (const int*)d_in[1];
    const int*   batch = (const int*)d_in[2];
    const float* embW  = (const float*)d_in[3];
    const float* embb  = (const float*)d_in[4];
    const float* embg  = (const float*)d_in[5];
    const float* embbe = (const float*)d_in[6];
    const float* msgW  = (const float*)d_in[7];
    const float* msgb  = (const float*)d_in[8];
    const float* attW  = (const float*)d_in[9];
    const float* attb  = (const float*)d_in[10];
    const float* Wih   = (const float*)d_in[11];
    const float* bih   = (const float*)d_in[12];
    const float* Whh   = (const float*)d_in[13];
    const float* bhh   = (const float*)d_in[14];
    const float* bng   = (const float*)d_in[15];
    const float* bnb   = (const float*)d_in[16];
    const float* roW1  = (const float*)d_in[17];
    const float* rob1  = (const float*)d_in[18];
    const float* roW2  = (const float*)d_in[19];
    const float* rob2  = (const float*)d_in[20];
    const int* src = ei;
    const int* dst = ei + NE;
    float* out = (float*)d_out;

    float* w = (float*)d_ws;
    const size_t NH = (size_t)NN * HID;      // 6.4M floats
    float* x    = w;
    float* y    = x + NH;
    float* m    = y + NH;
    float* agg  = m + NH;
    float* as_  = agg + NH;
    float* ad_  = as_ + NN;
    float* ss   = ad_ + NN;                  // 256 floats: scale|shift
    float* gr   = ss + 256;                  // 128*128
    double* bnsum = (double*)(gr + NGRAPHS * HID);  // 256 doubles: sum|sumsq

    hipMemsetAsync(bnsum, 0, 256 * sizeof(double), stream);
    k_embed<<<NN / TN, 256, 0, stream>>>(nf, embW, embb, y, bnsum);
    k_bnfin<<<1, 128, 0, stream>>>(bnsum, embg, embbe, ss);
    k_bnapply<<<(int)(NH / 1024), 256, 0, stream>>>(y, ss, x);

    for (int l = 0; l < NLAYERS; l++) {
        k_node_pre<<<NN / TN, 256, 0, stream>>>(
            x, msgW + (size_t)l * HID * HID, msgb + (size_t)l * HID,
            attW + (size_t)l * 256, m, as_, ad_);
        hipMemsetAsync(agg, 0, NH * sizeof(float), stream);
        k_edge<<<NE / 8, 256, 0, stream>>>(src, dst, m, as_, ad_, attb, l, agg);
        hipMemsetAsync(bnsum, 0, 256 * sizeof(double), stream);
        k_gru<<<NN / TN, 256, 0, stream>>>(
            agg, x, Wih + (size_t)l * 384 * HID, bih + (size_t)l * 384,
            Whh + (size_t)l * 384 * HID, bhh + (size_t)l * 384, y, bnsum);
        k_bnfin<<<1, 128, 0, stream>>>(bnsum, bng + (size_t)l * HID, bnb + (size_t)l * HID, ss);
        k_bnapply<<<(int)(NH / 1024), 256, 0, stream>>>(y, ss, x);
    }

    hipMemsetAsync(gr, 0, NGRAPHS * HID * sizeof(float), stream);
    k_pool<<<NN / 8, 256, 0, stream>>>(x, batch, gr);
    k_readout<<<NGRAPHS, 64, 0, stream>>>(gr, roW1, rob1, roW2, rob2, out);
}

// Round 2
// 2338.354 us; speedup vs baseline: 2.5407x; 2.5407x over previous
//
#include <hip/hip_runtime.h>
#include <math.h>

#define NN 50000
#define NE 600000
#define ADIM 75
#define HID 128
#define NLAYERS 4
#define NGRAPHS 128
#define BN_EPS 1e-5f
#define TN 16   // nodes per block in tiled node kernels

__device__ __forceinline__ float sigm(float v) { return 1.0f / (1.0f + __expf(-v)); }

// ---------------------------------------------------------------------------
// Embedding: y = relu(nf @ embW^T + embb), accumulate BN sums (double atomics)
// block 256 = 16 nodes x 16 f-groups; grid 3125
// ---------------------------------------------------------------------------
__global__ __launch_bounds__(256) void k_embed(
    const float* __restrict__ nf, const float* __restrict__ W,
    const float* __restrict__ b, float* __restrict__ y,
    double* __restrict__ bnsum)
{
    __shared__ float sNF[TN * 80];     // 75 padded to 80
    __shared__ float sW[128 * 76];     // 75 padded to 76
    __shared__ float sH[TN * 128];
    const int t = threadIdx.x;
    const int node0 = blockIdx.x * TN;

    for (int i = t; i < TN * ADIM; i += 256) {
        int r = i / ADIM, c = i - r * ADIM;
        sNF[r * 80 + c] = nf[node0 * ADIM + i];
    }
    for (int i = t; i < 128 * ADIM; i += 256) {
        int r = i / ADIM, c = i - r * ADIM;
        sW[r * 76 + c] = W[i];
    }
    __syncthreads();

    const int node = t >> 4, fg = t & 15;
    float acc[8];
#pragma unroll
    for (int j = 0; j < 8; j++) acc[j] = b[fg + 16 * j];

    const float* arow = &sNF[node * 80];
#pragma unroll 6
    for (int k = 0; k < 72; k += 4) {
        float4 a = *(const float4*)&arow[k];
#pragma unroll
        for (int j = 0; j < 8; j++) {
            float4 w = *(const float4*)&sW[(fg + 16 * j) * 76 + k];
            acc[j] += a.x * w.x + a.y * w.y + a.z * w.z + a.w * w.w;
        }
    }
    for (int k = 72; k < 75; k++) {
        float a = arow[k];
#pragma unroll
        for (int j = 0; j < 8; j++) acc[j] += a * sW[(fg + 16 * j) * 76 + k];
    }
#pragma unroll
    for (int j = 0; j < 8; j++) {
        float v = fmaxf(acc[j], 0.0f);
        int f = fg + 16 * j;
        sH[node * 128 + f] = v;
        y[(node0 + node) * HID + f] = v;
    }
    __syncthreads();
    if (t < 128) {
        float s = 0.f, s2 = 0.f;
#pragma unroll
        for (int n2 = 0; n2 < TN; n2++) { float v = sH[n2 * 128 + t]; s += v; s2 += v * v; }
        unsafeAtomicAdd(&bnsum[t], (double)s);
        unsafeAtomicAdd(&bnsum[128 + t], (double)s2);
    }
}

// ---------------------------------------------------------------------------
// BN finalize: scale/shift from double sums
// ---------------------------------------------------------------------------
__global__ void k_bnfin(const double* __restrict__ bnsum, const float* __restrict__ g,
                        const float* __restrict__ beta, float* __restrict__ ss)
{
    int f = threadIdx.x;
    double mean = bnsum[f] / (double)NN;
    double var  = bnsum[128 + f] / (double)NN - mean * mean;
    float inv = rsqrtf((float)var + BN_EPS);
    float sc = g[f] * inv;
    ss[f] = sc;
    ss[128 + f] = beta[f] - (float)mean * sc;
}

// ---------------------------------------------------------------------------
// Fused BN-apply + attention projections for the NEXT layer:
//   x = y*scale + shift ; as_[n] = x.attW[:128] ; ad_[n] = x.attW[128:]
// block 256 = 4 nodes x 64 lanes (float2/lane); grid 12500
// ---------------------------------------------------------------------------
__global__ __launch_bounds__(256) void k_bnx(
    const float* __restrict__ y, const float* __restrict__ ss,
    const float* __restrict__ attW, float* __restrict__ x,
    float* __restrict__ as_, float* __restrict__ ad_)
{
    const int t = threadIdx.x;
    const int n = blockIdx.x * 4 + (t >> 6);
    const int lane = t & 63;
    float2 sc = ((const float2*)ss)[lane];
    float2 sh = ((const float2*)(ss + 128))[lane];
    float2 v = ((const float2*)y)[(size_t)n * 64 + lane];
    float2 xv;
    xv.x = v.x * sc.x + sh.x;
    xv.y = v.y * sc.y + sh.y;
    ((float2*)x)[(size_t)n * 64 + lane] = xv;
    float2 aws = ((const float2*)attW)[lane];
    float2 awd = ((const float2*)(attW + 128))[lane];
    float pas = xv.x * aws.x + xv.y * aws.y;
    float pad = xv.x * awd.x + xv.y * awd.y;
#pragma unroll
    for (int msk = 32; msk >= 1; msk >>= 1) {
        pas += __shfl_xor(pas, msk);
        pad += __shfl_xor(pad, msk);
    }
    if (lane == 0) { as_[n] = pas; ad_[n] = pad; }
}

// ---------------------------------------------------------------------------
// Combined-weight precompute: Wc[l] = Wih[l] @ Wm[l]  [384x128],
//                             bmih[l] = Wih[l] @ bm[l] [384]
// grid 4*384 blocks x 128 threads
// ---------------------------------------------------------------------------
__global__ __launch_bounds__(128) void k_wc(
    const float* __restrict__ Wih, const float* __restrict__ Wm,
    const float* __restrict__ bm, float* __restrict__ Wc, float* __restrict__ bmih)
{
    __shared__ float sw[128];
    __shared__ float red[128];
    const int b = blockIdx.x;
    const int l = b / 384, r = b - l * 384;
    const int t = threadIdx.x;
    const float* wihrow = Wih + ((size_t)l * 384 + r) * 128;
    sw[t] = wihrow[t];
    __syncthreads();
    const float* wm = Wm + (size_t)l * 128 * 128;
    float acc = 0.f;
#pragma unroll 8
    for (int k = 0; k < 128; k++) acc += sw[k] * wm[k * 128 + t];
    Wc[((size_t)l * 384 + r) * 128 + t] = acc;
    red[t] = sw[t] * bm[l * 128 + t];
    __syncthreads();
#pragma unroll
    for (int off = 64; off >= 1; off >>= 1) {
        if (t < off) red[t] += red[t + off];
        __syncthreads();
    }
    if (t == 0) bmih[l * 384 + r] = red[0];
}

// ---------------------------------------------------------------------------
// CSR build: histogram, single-block scan, scatter
// ---------------------------------------------------------------------------
__global__ __launch_bounds__(256) void k_count(const int* __restrict__ dst, int* __restrict__ cnt)
{
    int e = blockIdx.x * 256 + threadIdx.x;
    if (e < NE) atomicAdd(&cnt[dst[e]], 1);
}

__global__ __launch_bounds__(1024) void k_scan(
    const int* __restrict__ cnt, int* __restrict__ rowptr, int* __restrict__ wptr)
{
    __shared__ int s[1024];
    const int t = threadIdx.x;
    const int CH = 49;                       // 1024*49 >= 50000
    int begin = t * CH;
    int end = begin + CH; if (end > NN) end = NN;
    int sum = 0;
    for (int i = begin; i < end; i++) sum += cnt[i];
    s[t] = sum;
    __syncthreads();
    for (int off = 1; off < 1024; off <<= 1) {
        int v = (t >= off) ? s[t - off] : 0;
        __syncthreads();
        s[t] += v;
        __syncthreads();
    }
    int run = s[t] - sum;                    // exclusive prefix of this chunk
    for (int i = begin; i < end; i++) {
        rowptr[i] = run; wptr[i] = run;
        run += cnt[i];
    }
    if (t == 1023) rowptr[NN] = s[1023];
}

__global__ __launch_bounds__(256) void k_scatter(
    const int* __restrict__ src, const int* __restrict__ dst,
    int* __restrict__ wptr, int* __restrict__ ssrc)
{
    int e = blockIdx.x * 256 + threadIdx.x;
    if (e < NE) {
        int d = dst[e];
        int pos = atomicAdd(&wptr[d], 1);
        ssrc[pos] = src[e];
    }
}

// ---------------------------------------------------------------------------
// Gather-aggregate (no atomics): per node d,
//   aggx[d] = sum_e att_e * x[src_e] ; sumatt[d] = sum_e att_e
// att_e = sigmoid(as_[s] + ad_[d] + attb[l])
// block 256 = 8 nodes x 32 lanes (float4/lane); grid 6250
// ---------------------------------------------------------------------------
__global__ __launch_bounds__(256) void k_gather(
    const int* __restrict__ rowptr, const int* __restrict__ ssrc,
    const float* __restrict__ x, const float* __restrict__ as_,
    const float* __restrict__ ad_, const float* __restrict__ attb, int l,
    float* __restrict__ aggx, float* __restrict__ sumatt)
{
    const int t = threadIdx.x;
    const int n = blockIdx.x * 8 + (t >> 5);
    const int lane = t & 31;
    const int r0 = rowptr[n], r1 = rowptr[n + 1];
    const float adv = ad_[n] + attb[l];
    float4 acc = make_float4(0.f, 0.f, 0.f, 0.f);
    float satt = 0.f;
    for (int i = r0; i < r1; i++) {
        int s = ssrc[i];
        float att = sigm(as_[s] + adv);
        float4 v = ((const float4*)x)[(size_t)s * 32 + lane];
        acc.x += v.x * att; acc.y += v.y * att;
        acc.z += v.z * att; acc.w += v.w * att;
        satt += att;
    }
    ((float4*)aggx)[(size_t)n * 32 + lane] = acc;
    if (lane == 0) sumatt[n] = satt;
}

// ---------------------------------------------------------------------------
// Fused GRU: gi = aggx@Wc^T + sumatt*bmih + bih, gh = x@Whh^T + bhh,
//            gates, h_new, BN sums
// block 256 = 16 nodes x 16 f-groups; grid 3125
// 12 weight-chunk passes (6 for Wc, 6 for Whh), 64 rows x 128 K each in LDS
// ---------------------------------------------------------------------------
__global__ __launch_bounds__(256) void k_gru(
    const float* __restrict__ aggx, const float* __restrict__ sumatt,
    const float* __restrict__ x,
    const float* __restrict__ Wc, const float* __restrict__ bmih,
    const float* __restrict__ bih,
    const float* __restrict__ Whh, const float* __restrict__ bhh,
    float* __restrict__ y, double* __restrict__ bnsum)
{
    __shared__ float sA[TN * 132];           // aggx tile; reused as h-staging at end
    __shared__ float sX[TN * 132];
    __shared__ float sW[64 * 132];
    const int t = threadIdx.x;
    const int node0 = blockIdx.x * TN;
    {
        const float4* sa = (const float4*)(aggx + (size_t)node0 * HID);
        const float4* sx = (const float4*)(x + (size_t)node0 * HID);
#pragma unroll
        for (int i = 0; i < 2; i++) {
            int f4 = t + i * 256;
            int r = f4 >> 5, c = (f4 & 31) * 4;
            *(float4*)&sA[r * 132 + c] = sa[f4];
            *(float4*)&sX[r * 132 + c] = sx[f4];
        }
    }
    const int node = t >> 4, fg = t & 15;
    const float sa_n = sumatt[node0 + node];

    float acci[24], acch[24];
#pragma unroll
    for (int gj = 0; gj < 24; gj++) {
        int gate = gj >> 3, j = gj & 7;
        int row = gate * 128 + fg + 16 * j;
        acci[gj] = bih[row] + sa_n * bmih[row];
        acch[gj] = bhh[row];
    }

#pragma unroll
    for (int pass = 0; pass < 12; pass++) {
        __syncthreads();
        const int pm = (pass < 6) ? pass : (pass - 6);
        const float4* wsrc = (const float4*)(((pass < 6) ? Wc : Whh) + pm * 64 * HID);
#pragma unroll
        for (int i = 0; i < 8; i++) {
            int f4 = t + i * 256;
            int r = f4 >> 5, c = (f4 & 31) * 4;
            *(float4*)&sW[r * 132 + c] = wsrc[f4];
        }
        __syncthreads();
        const float* arow = (pass < 6) ? &sA[node * 132] : &sX[node * 132];
        float t0 = 0.f, t1 = 0.f, t2 = 0.f, t3 = 0.f;
#pragma unroll 4
        for (int k = 0; k < 128; k += 4) {
            float4 a = *(const float4*)&arow[k];
            float4 w0 = *(const float4*)&sW[(fg +  0) * 132 + k];
            float4 w1 = *(const float4*)&sW[(fg + 16) * 132 + k];
            float4 w2 = *(const float4*)&sW[(fg + 32) * 132 + k];
            float4 w3 = *(const float4*)&sW[(fg + 48) * 132 + k];
            t0 += a.x * w0.x + a.y * w0.y + a.z * w0.z + a.w * w0.w;
            t1 += a.x * w1.x + a.y * w1.y + a.z * w1.z + a.w * w1.w;
            t2 += a.x * w2.x + a.y * w2.y + a.z * w2.z + a.w * w2.w;
            t3 += a.x * w3.x + a.y * w3.y + a.z * w3.z + a.w * w3.w;
        }
        float* acc = (pass < 6) ? acci : acch;   // folded: pass is compile-time
        const int base = pm * 4;                 // = gate*8 + fhalf*4
        acc[base + 0] += t0; acc[base + 1] += t1;
        acc[base + 2] += t2; acc[base + 3] += t3;
    }

#pragma unroll
    for (int j = 0; j < 8; j++) {
        int f = fg + 16 * j;
        float r = sigm(acci[j] + acch[j]);
        float z = sigm(acci[8 + j] + acch[8 + j]);
        float n = tanhf(acci[16 + j] + r * acch[16 + j]);
        float xv = sX[node * 132 + f];
        float h = (1.0f - z) * n + z * xv;
        sA[node * 128 + f] = h;                  // reuse sA as h staging
        y[(node0 + node) * HID + f] = h;
    }
    __syncthreads();
    if (t < 128) {
        float s = 0.f, s2 = 0.f;
#pragma unroll
        for (int n2 = 0; n2 < TN; n2++) { float v = sA[n2 * 128 + t]; s += v; s2 += v * v; }
        unsafeAtomicAdd(&bnsum[t], (double)s);
        unsafeAtomicAdd(&bnsum[128 + t], (double)s2);
    }
}

// ---------------------------------------------------------------------------
// Graph sum-pool: gr[batch[n]] += x[n]    block 256 = 8 nodes x 32 lanes
// ---------------------------------------------------------------------------
__global__ __launch_bounds__(256) void k_pool(
    const float* __restrict__ x, const int* __restrict__ batch, float* __restrict__ gr)
{
    const int t = threadIdx.x;
    const int n = blockIdx.x * 8 + (t >> 5);
    const int lane = t & 31;
    const int g = batch[n];
    float4 v = *(const float4*)&x[(size_t)n * HID + lane * 4];
    float* p = &gr[(size_t)g * HID + lane * 4];
    unsafeAtomicAdd(p + 0, v.x);
    unsafeAtomicAdd(p + 1, v.y);
    unsafeAtomicAdd(p + 2, v.z);
    unsafeAtomicAdd(p + 3, v.w);
}

// ---------------------------------------------------------------------------
// Readout: out[g] = relu(gr[g] @ W1^T + b1) @ W2^T + b2   (128 blocks x 64)
// ---------------------------------------------------------------------------
__global__ __launch_bounds__(64) void k_readout(
    const float* __restrict__ gr, const float* __restrict__ W1,
    const float* __restrict__ b1, const float* __restrict__ W2,
    const float* __restrict__ b2, float* __restrict__ out)
{
    const int g = blockIdx.x, j = threadIdx.x;
    float acc = b1[j];
    const float4* grow = (const float4*)&gr[g * HID];
    const float4* wrow = (const float4*)&W1[j * HID];
#pragma unroll
    for (int k4 = 0; k4 < 32; k4++) {
        float4 a = grow[k4], w = wrow[k4];
        acc += a.x * w.x + a.y * w.y + a.z * w.z + a.w * w.w;
    }
    float h = fmaxf(acc, 0.0f) * W2[j];
#pragma unroll
    for (int msk = 32; msk >= 1; msk >>= 1) h += __shfl_xor(h, msk);
    if (j == 0) out[g] = h + b2[0];
}

// ---------------------------------------------------------------------------
extern "C" void kernel_launch(void* const* d_in, const int* in_sizes, int n_in,
                              void* d_out, int out_size, void* d_ws, size_t ws_size,
                              hipStream_t stream)
{
    const float* nf    = (const float*)d_in[0];
    const int*   ei    = (const int*)d_in[1];
    const int*   batch = (const int*)d_in[2];
    const float* embW  = (const float*)d_in[3];
    const float* embb  = (const float*)d_in[4];
    const float* embg  = (const float*)d_in[5];
    const float* embbe = (const float*)d_in[6];
    const float* msgW  = (const float*)d_in[7];
    const float* msgb  = (const float*)d_in[8];
    const float* attW  = (const float*)d_in[9];
    const float* attb  = (const float*)d_in[10];
    const float* Wih   = (const float*)d_in[11];
    const float* bih   = (const float*)d_in[12];
    const float* Whh   = (const float*)d_in[13];
    const float* bhh   = (const float*)d_in[14];
    const float* bng   = (const float*)d_in[15];
    const float* bnb   = (const float*)d_in[16];
    const float* roW1  = (const float*)d_in[17];
    const float* rob1  = (const float*)d_in[18];
    const float* roW2  = (const float*)d_in[19];
    const float* rob2  = (const float*)d_in[20];
    const int* src = ei;
    const int* dst = ei + NE;
    float* out = (float*)d_out;

    // ---- workspace layout (bnsum first for 8B alignment) ----
    char* base = (char*)d_ws;
    const size_t NH = (size_t)NN * HID;      // 6.4M floats
    double* bnsum = (double*)base;           // 256 doubles
    float* x     = (float*)(base + 2048);
    float* y     = x + NH;
    float* aggx  = y + NH;
    float* as_   = aggx + NH;
    float* ad_   = as_ + NN;
    float* sumatt= ad_ + NN;
    float* ss    = sumatt + NN;              // 256: scale|shift
    float* gr    = ss + 256;                 // 128*128
    float* Wc    = gr + NGRAPHS * HID;       // 4*384*128
    float* bmih  = Wc + 4 * 384 * 128;       // 4*384
    int* rowptr  = (int*)(bmih + 4 * 384);   // NN+1
    int* wptr    = rowptr + NN + 1;          // NN
    int* cnt     = wptr + NN;                // NN
    int* ssrc    = cnt + NN;                 // NE

    // ---- once-per-call precompute: combined weights + CSR ----
    k_wc<<<4 * 384, 128, 0, stream>>>(Wih, msgW, msgb, Wc, bmih);
    hipMemsetAsync(cnt, 0, NN * sizeof(int), stream);
    k_count<<<(NE + 255) / 256, 256, 0, stream>>>(dst, cnt);
    k_scan<<<1, 1024, 0, stream>>>(cnt, rowptr, wptr);
    k_scatter<<<(NE + 255) / 256, 256, 0, stream>>>(src, dst, wptr, ssrc);

    // ---- embedding + BN + att-proj for layer 0 ----
    hipMemsetAsync(bnsum, 0, 256 * sizeof(double), stream);
    k_embed<<<NN / TN, 256, 0, stream>>>(nf, embW, embb, y, bnsum);
    k_bnfin<<<1, 128, 0, stream>>>(bnsum, embg, embbe, ss);
    k_bnx<<<NN / 4, 256, 0, stream>>>(y, ss, attW, x, as_, ad_);

    for (int l = 0; l < NLAYERS; l++) {
        k_gather<<<NN / 8, 256, 0, stream>>>(rowptr, ssrc, x, as_, ad_, attb, l, aggx, sumatt);
        hipMemsetAsync(bnsum, 0, 256 * sizeof(double), stream);
        k_gru<<<NN / TN, 256, 0, stream>>>(
            aggx, sumatt, x,
            Wc + (size_t)l * 384 * HID, bmih + (size_t)l * 384, bih + (size_t)l * 384,
            Whh + (size_t)l * 384 * HID, bhh + (size_t)l * 384, y, bnsum);
        k_bnfin<<<1, 128, 0, stream>>>(bnsum, bng + (size_t)l * HID, bnb + (size_t)l * HID, ss);
        const float* attW_next = attW + (size_t)((l + 1 < NLAYERS) ? l + 1 : l) * 256;
        k_bnx<<<NN / 4, 256, 0, stream>>>(y, ss, attW_next, x, as_, ad_);
    }

    hipMemsetAsync(gr, 0, NGRAPHS * HID * sizeof(float), stream);
    k_pool<<<NN / 8, 256, 0, stream>>>(x, batch, gr);
    k_readout<<<NGRAPHS, 64, 0, stream>>>(gr, roW1, rob1, roW2, rob2, out);
}

// Round 3
// 1134.073 us; speedup vs baseline: 5.2387x; 2.0619x over previous
//
#include <hip/hip_runtime.h>
#include <math.h>

#define NN 50000
#define NE 600000
#define ADIM 75
#define HID 128
#define NLAYERS 4
#define NGRAPHS 128
#define BN_EPS 1e-5f
#define TN 16   // nodes per block in tiled node kernels

typedef short bhalf8 __attribute__((ext_vector_type(8)));
typedef float floatx4 __attribute__((ext_vector_type(4)));

__device__ __forceinline__ float sigm(float v) { return 1.0f / (1.0f + __expf(-v)); }

// fp32 -> bf16 with round-to-nearest-even
__device__ __forceinline__ short f2bf(float f) {
    unsigned u = __builtin_bit_cast(unsigned, f);
    u = (u + 0x7FFFu + ((u >> 16) & 1u)) >> 16;
    return (short)u;
}

// ---------------------------------------------------------------------------
// Embedding: y = relu(nf @ embW^T + embb), accumulate BN sums (double atomics)
// block 256 = 16 nodes x 16 f-groups; grid 3125
// ---------------------------------------------------------------------------
__global__ __launch_bounds__(256) void k_embed(
    const float* __restrict__ nf, const float* __restrict__ W,
    const float* __restrict__ b, float* __restrict__ y,
    double* __restrict__ bnsum)
{
    __shared__ float sNF[TN * 80];     // 75 padded to 80
    __shared__ float sW[128 * 76];     // 75 padded to 76
    __shared__ float sH[TN * 128];
    const int t = threadIdx.x;
    const int node0 = blockIdx.x * TN;

    for (int i = t; i < TN * ADIM; i += 256) {
        int r = i / ADIM, c = i - r * ADIM;
        sNF[r * 80 + c] = nf[node0 * ADIM + i];
    }
    for (int i = t; i < 128 * ADIM; i += 256) {
        int r = i / ADIM, c = i - r * ADIM;
        sW[r * 76 + c] = W[i];
    }
    __syncthreads();

    const int node = t >> 4, fg = t & 15;
    float acc[8];
#pragma unroll
    for (int j = 0; j < 8; j++) acc[j] = b[fg + 16 * j];

    const float* arow = &sNF[node * 80];
#pragma unroll 6
    for (int k = 0; k < 72; k += 4) {
        float4 a = *(const float4*)&arow[k];
#pragma unroll
        for (int j = 0; j < 8; j++) {
            float4 w = *(const float4*)&sW[(fg + 16 * j) * 76 + k];
            acc[j] += a.x * w.x + a.y * w.y + a.z * w.z + a.w * w.w;
        }
    }
    for (int k = 72; k < 75; k++) {
        float a = arow[k];
#pragma unroll
        for (int j = 0; j < 8; j++) acc[j] += a * sW[(fg + 16 * j) * 76 + k];
    }
#pragma unroll
    for (int j = 0; j < 8; j++) {
        float v = fmaxf(acc[j], 0.0f);
        int f = fg + 16 * j;
        sH[node * 128 + f] = v;
        y[(node0 + node) * HID + f] = v;
    }
    __syncthreads();
    if (t < 128) {
        float s = 0.f, s2 = 0.f;
#pragma unroll
        for (int n2 = 0; n2 < TN; n2++) { float v = sH[n2 * 128 + t]; s += v; s2 += v * v; }
        unsafeAtomicAdd(&bnsum[t], (double)s);
        unsafeAtomicAdd(&bnsum[128 + t], (double)s2);
    }
}

// ---------------------------------------------------------------------------
// BN finalize: scale/shift from double sums
// ---------------------------------------------------------------------------
__global__ void k_bnfin(const double* __restrict__ bnsum, const float* __restrict__ g,
                        const float* __restrict__ beta, float* __restrict__ ss)
{
    int f = threadIdx.x;
    double mean = bnsum[f] / (double)NN;
    double var  = bnsum[128 + f] / (double)NN - mean * mean;
    float inv = rsqrtf((float)var + BN_EPS);
    float sc = g[f] * inv;
    ss[f] = sc;
    ss[128 + f] = beta[f] - (float)mean * sc;
}

// ---------------------------------------------------------------------------
// Fused BN-apply + attention projections for the NEXT layer:
//   x = y*scale + shift ; as_[n] = x.attW[:128] ; ad_[n] = x.attW[128:]
// block 256 = 4 nodes x 64 lanes (float2/lane); grid 12500
// ---------------------------------------------------------------------------
__global__ __launch_bounds__(256) void k_bnx(
    const float* __restrict__ y, const float* __restrict__ ss,
    const float* __restrict__ attW, float* __restrict__ x,
    float* __restrict__ as_, float* __restrict__ ad_)
{
    const int t = threadIdx.x;
    const int n = blockIdx.x * 4 + (t >> 6);
    const int lane = t & 63;
    float2 sc = ((const float2*)ss)[lane];
    float2 sh = ((const float2*)(ss + 128))[lane];
    float2 v = ((const float2*)y)[(size_t)n * 64 + lane];
    float2 xv;
    xv.x = v.x * sc.x + sh.x;
    xv.y = v.y * sc.y + sh.y;
    ((float2*)x)[(size_t)n * 64 + lane] = xv;
    float2 aws = ((const float2*)attW)[lane];
    float2 awd = ((const float2*)(attW + 128))[lane];
    float pas = xv.x * aws.x + xv.y * aws.y;
    float pad = xv.x * awd.x + xv.y * awd.y;
#pragma unroll
    for (int msk = 32; msk >= 1; msk >>= 1) {
        pas += __shfl_xor(pas, msk);
        pad += __shfl_xor(pad, msk);
    }
    if (lane == 0) { as_[n] = pas; ad_[n] = pad; }
}

// ---------------------------------------------------------------------------
// Combined-weight precompute: Wc[l] = Wih[l] @ Wm[l]  [384x128],
//                             bmih[l] = Wih[l] @ bm[l] [384]
// grid 4*384 blocks x 128 threads
// ---------------------------------------------------------------------------
__global__ __launch_bounds__(128) void k_wc(
    const float* __restrict__ Wih, const float* __restrict__ Wm,
    const float* __restrict__ bm, float* __restrict__ Wc, float* __restrict__ bmih)
{
    __shared__ float sw[128];
    __shared__ float red[128];
    const int b = blockIdx.x;
    const int l = b / 384, r = b - l * 384;
    const int t = threadIdx.x;
    const float* wihrow = Wih + ((size_t)l * 384 + r) * 128;
    sw[t] = wihrow[t];
    __syncthreads();
    const float* wm = Wm + (size_t)l * 128 * 128;
    float acc = 0.f;
#pragma unroll 8
    for (int k = 0; k < 128; k++) acc += sw[k] * wm[k * 128 + t];
    Wc[((size_t)l * 384 + r) * 128 + t] = acc;
    red[t] = sw[t] * bm[l * 128 + t];
    __syncthreads();
#pragma unroll
    for (int off = 64; off >= 1; off >>= 1) {
        if (t < off) red[t] += red[t + off];
        __syncthreads();
    }
    if (t == 0) bmih[l * 384 + r] = red[0];
}

// ---------------------------------------------------------------------------
// Convert Wc (fp32, [L][384][128]) and Whh to bf16 in MFMA B-fragment order:
//   layout [gate(3)][tc(8)][kb(4)][quad(4)][n(16)][j(8)] per layer-matrix
//   element = W[gate*128 + tc*16 + n][kb*32 + quad*8 + j]
// grid 8 mats * 192 blocks x 256 threads
// ---------------------------------------------------------------------------
__global__ __launch_bounds__(256) void k_frag(
    const float* __restrict__ Wc, const float* __restrict__ Whh,
    short* __restrict__ wcb, short* __restrict__ whhb)
{
    const int b = blockIdx.x;
    const int mat = b / 192;
    const int e = (b - mat * 192) * 256 + threadIdx.x;   // 0..49151
    const int l = mat >> 1, which = mat & 1;
    const float* src = which ? (Whh + (size_t)l * 49152) : (Wc + (size_t)l * 49152);
    short* dst = which ? (whhb + (size_t)l * 49152) : (wcb + (size_t)l * 49152);
    int j = e & 7, n = (e >> 3) & 15, quad = (e >> 7) & 3;
    int kb = (e >> 9) & 3, tc = (e >> 11) & 7, g = (e >> 14) & 3;
    int row = g * 128 + tc * 16 + n;
    int kk = kb * 32 + quad * 8 + j;
    dst[e] = f2bf(src[row * 128 + kk]);
}

// ---------------------------------------------------------------------------
// CSR build: histogram, single-block scan, scatter
// ---------------------------------------------------------------------------
__global__ __launch_bounds__(256) void k_count(const int* __restrict__ dst, int* __restrict__ cnt)
{
    int e = blockIdx.x * 256 + threadIdx.x;
    if (e < NE) atomicAdd(&cnt[dst[e]], 1);
}

__global__ __launch_bounds__(1024) void k_scan(
    const int* __restrict__ cnt, int* __restrict__ rowptr, int* __restrict__ wptr)
{
    __shared__ int s[1024];
    const int t = threadIdx.x;
    const int CH = 49;                       // 1024*49 >= 50000
    int begin = t * CH;
    int end = begin + CH; if (end > NN) end = NN;
    int sum = 0;
    for (int i = begin; i < end; i++) sum += cnt[i];
    s[t] = sum;
    __syncthreads();
    for (int off = 1; off < 1024; off <<= 1) {
        int v = (t >= off) ? s[t - off] : 0;
        __syncthreads();
        s[t] += v;
        __syncthreads();
    }
    int run = s[t] - sum;                    // exclusive prefix of this chunk
    for (int i = begin; i < end; i++) {
        rowptr[i] = run; wptr[i] = run;
        run += cnt[i];
    }
    if (t == 1023) rowptr[NN] = s[1023];
}

__global__ __launch_bounds__(256) void k_scatter(
    const int* __restrict__ src, const int* __restrict__ dst,
    int* __restrict__ wptr, int* __restrict__ ssrc)
{
    int e = blockIdx.x * 256 + threadIdx.x;
    if (e < NE) {
        int d = dst[e];
        int pos = atomicAdd(&wptr[d], 1);
        ssrc[pos] = src[e];
    }
}

// ---------------------------------------------------------------------------
// Gather-aggregate (no atomics): per node d,
//   aggx[d] = sum_e att_e * x[src_e] ; sumatt[d] = sum_e att_e
// att_e = sigmoid(as_[s] + ad_[d] + attb[l])
// block 256 = 8 nodes x 32 lanes (float4/lane); grid 6250
// ---------------------------------------------------------------------------
__global__ __launch_bounds__(256) void k_gather(
    const int* __restrict__ rowptr, const int* __restrict__ ssrc,
    const float* __restrict__ x, const float* __restrict__ as_,
    const float* __restrict__ ad_, const float* __restrict__ attb, int l,
    float* __restrict__ aggx, float* __restrict__ sumatt)
{
    const int t = threadIdx.x;
    const int n = blockIdx.x * 8 + (t >> 5);
    const int lane = t & 31;
    const int r0 = rowptr[n], r1 = rowptr[n + 1];
    const float adv = ad_[n] + attb[l];
    float4 acc = make_float4(0.f, 0.f, 0.f, 0.f);
    float satt = 0.f;
    for (int i = r0; i < r1; i++) {
        int s = ssrc[i];
        float att = sigm(as_[s] + adv);
        float4 v = ((const float4*)x)[(size_t)s * 32 + lane];
        acc.x += v.x * att; acc.y += v.y * att;
        acc.z += v.z * att; acc.w += v.w * att;
        satt += att;
    }
    ((float4*)aggx)[(size_t)n * 32 + lane] = acc;
    if (lane == 0) sumatt[n] = satt;
}

// ---------------------------------------------------------------------------
// MFMA GRU: gi = aggx@Wc^T + sumatt*bmih + bih ; gh = x@Whh^T + bhh
//           gates, h_new, BN sums.
// block 256 = 4 waves x 16 nodes each (64 nodes/block); grid 782.
// 6 rounds: (Wc,Whh) x gates (r,n,z). W chunks (32KB bf16, frag-ordered)
// streamed via global_load_lds width=16. A-frags global->reg, bf16 RNE.
// C/D layout: col=lane&15 (output f within 16-tile), row=quad*4+reg (node).
// ---------------------------------------------------------------------------
#define LOADW(PTR)                                                            \
    __syncthreads();                                                          \
    _Pragma("unroll")                                                         \
    for (int i = 0; i < 8; i++) {                                             \
        const short* gp = (PTR) + ((wave * 8 + i) * 64 + lane) * 8;           \
        short* lp = sW + (wave * 8 + i) * 512;                                \
        __builtin_amdgcn_global_load_lds(                                     \
            (__attribute__((address_space(1))) void*)gp,                      \
            (__attribute__((address_space(3))) void*)lp, 16, 0, 0);           \
    }                                                                         \
    __syncthreads();

#define MM(AF, ACC)                                                           \
    _Pragma("unroll")                                                         \
    for (int tc = 0; tc < 8; tc++) {                                          \
        _Pragma("unroll")                                                     \
        for (int kb = 0; kb < 4; kb++) {                                      \
            bhalf8 bf = *(const bhalf8*)&sW[(((tc * 4 + kb) * 4 + quad) * 16 + col) * 8]; \
            ACC[tc] = __builtin_amdgcn_mfma_f32_16x16x32_bf16(AF[kb], bf, ACC[tc], 0, 0, 0); \
        }                                                                     \
    }

__global__ __launch_bounds__(256) void k_gru(
    const float* __restrict__ aggx, const float* __restrict__ sumatt,
    const float* __restrict__ x,
    const short* __restrict__ wcb, const float* __restrict__ bmih,
    const float* __restrict__ bih,
    const short* __restrict__ whhb, const float* __restrict__ bhh,
    float* __restrict__ y, double* __restrict__ bnsum)
{
    __shared__ __align__(16) short sW[128 * 128];   // 32 KB; reused as h-stage fp32
    const int t = threadIdx.x;
    const int wave = t >> 6, lane = t & 63;
    const int col = lane & 15, quad = (lane >> 4) & 3;
    const int node0 = blockIdx.x * 64;

    // ---- A-fragments (global -> bf16 regs), A[m=lane&15][k=quad*8+j] ----
    const int anode = node0 + wave * 16 + col;
    bhalf8 afA[4], afX[4];
#pragma unroll
    for (int kb = 0; kb < 4; kb++) {
        const float* pa = aggx + (size_t)anode * HID + kb * 32 + quad * 8;
        const float* px = x    + (size_t)anode * HID + kb * 32 + quad * 8;
        float4 a0 = *(const float4*)pa, a1 = *(const float4*)(pa + 4);
        float4 x0 = *(const float4*)px, x1 = *(const float4*)(px + 4);
        afA[kb][0] = f2bf(a0.x); afA[kb][1] = f2bf(a0.y);
        afA[kb][2] = f2bf(a0.z); afA[kb][3] = f2bf(a0.w);
        afA[kb][4] = f2bf(a1.x); afA[kb][5] = f2bf(a1.y);
        afA[kb][6] = f2bf(a1.z); afA[kb][7] = f2bf(a1.w);
        afX[kb][0] = f2bf(x0.x); afX[kb][1] = f2bf(x0.y);
        afX[kb][2] = f2bf(x0.z); afX[kb][3] = f2bf(x0.w);
        afX[kb][4] = f2bf(x1.x); afX[kb][5] = f2bf(x1.y);
        afX[kb][6] = f2bf(x1.z); afX[kb][7] = f2bf(x1.w);
    }
    float sa[4];
#pragma unroll
    for (int e = 0; e < 4; e++) sa[e] = sumatt[node0 + wave * 16 + quad * 4 + e];

    floatx4 acc_i[8], acc_h[8], gr_[8], gn_[8];

    // ================= gate r (g=0) =================
#pragma unroll
    for (int tc = 0; tc < 8; tc++) {
        int f = 0 * 128 + tc * 16 + col;
        float bi = bih[f], bm = bmih[f], bh = bhh[f];
        acc_i[tc] = (floatx4){bi + sa[0] * bm, bi + sa[1] * bm, bi + sa[2] * bm, bi + sa[3] * bm};
        acc_h[tc] = (floatx4){bh, bh, bh, bh};
    }
    LOADW(wcb + 0 * 16384); MM(afA, acc_i);
    LOADW(whhb + 0 * 16384); MM(afX, acc_h);
#pragma unroll
    for (int tc = 0; tc < 8; tc++)
#pragma unroll
        for (int e = 0; e < 4; e++)
            gr_[tc][e] = sigm(acc_i[tc][e] + acc_h[tc][e]);

    // ================= gate n (g=2) =================
#pragma unroll
    for (int tc = 0; tc < 8; tc++) {
        int f = 2 * 128 + tc * 16 + col;
        float bi = bih[f], bm = bmih[f], bh = bhh[f];
        acc_i[tc] = (floatx4){bi + sa[0] * bm, bi + sa[1] * bm, bi + sa[2] * bm, bi + sa[3] * bm};
        acc_h[tc] = (floatx4){bh, bh, bh, bh};
    }
    LOADW(wcb + 2 * 16384); MM(afA, acc_i);
    LOADW(whhb + 2 * 16384); MM(afX, acc_h);
#pragma unroll
    for (int tc = 0; tc < 8; tc++)
#pragma unroll
        for (int e = 0; e < 4; e++)
            gn_[tc][e] = tanhf(acc_i[tc][e] + gr_[tc][e] * acc_h[tc][e]);

    // ================= gate z (g=1) + h =================
#pragma unroll
    for (int tc = 0; tc < 8; tc++) {
        int f = 1 * 128 + tc * 16 + col;
        float bi = bih[f], bm = bmih[f], bh = bhh[f];
        acc_i[tc] = (floatx4){bi + sa[0] * bm, bi + sa[1] * bm, bi + sa[2] * bm, bi + sa[3] * bm};
        acc_h[tc] = (floatx4){bh, bh, bh, bh};
    }
    LOADW(wcb + 1 * 16384); MM(afA, acc_i);
    LOADW(whhb + 1 * 16384); MM(afX, acc_h);

    __syncthreads();                          // done reading sW as weights
    float* hst = (float*)sW;                  // 64 x 128 fp32 = 32 KB
#pragma unroll
    for (int tc = 0; tc < 8; tc++) {
#pragma unroll
        for (int e = 0; e < 4; e++) {
            float z = sigm(acc_i[tc][e] + acc_h[tc][e]);
            int nd = node0 + wave * 16 + quad * 4 + e;
            float xv = x[(size_t)nd * HID + tc * 16 + col];
            float h = (1.0f - z) * gn_[tc][e] + z * xv;
            hst[(wave * 16 + quad * 4 + e) * 128 + tc * 16 + col] = h;
        }
    }
    __syncthreads();

    // coalesced y write
#pragma unroll
    for (int i = 0; i < 32; i++) {
        int idx = t + i * 256;
        if (node0 + (idx >> 7) < NN) y[(size_t)node0 * HID + idx] = hst[idx];
    }
    // BN partial sums
    if (t < 128) {
        int count = NN - node0; if (count > 64) count = 64;
        float s = 0.f, s2 = 0.f;
        for (int m = 0; m < count; m++) { float v = hst[m * 128 + t]; s += v; s2 += v * v; }
        unsafeAtomicAdd(&bnsum[t], (double)s);
        unsafeAtomicAdd(&bnsum[128 + t], (double)s2);
    }
}

// ---------------------------------------------------------------------------
// Graph sum-pool: gr[batch[n]] += x[n]    block 256 = 8 nodes x 32 lanes
// ---------------------------------------------------------------------------
__global__ __launch_bounds__(256) void k_pool(
    const float* __restrict__ x, const int* __restrict__ batch, float* __restrict__ gr)
{
    const int t = threadIdx.x;
    const int n = blockIdx.x * 8 + (t >> 5);
    const int lane = t & 31;
    const int g = batch[n];
    float4 v = *(const float4*)&x[(size_t)n * HID + lane * 4];
    float* p = &gr[(size_t)g * HID + lane * 4];
    unsafeAtomicAdd(p + 0, v.x);
    unsafeAtomicAdd(p + 1, v.y);
    unsafeAtomicAdd(p + 2, v.z);
    unsafeAtomicAdd(p + 3, v.w);
}

// ---------------------------------------------------------------------------
// Readout: out[g] = relu(gr[g] @ W1^T + b1) @ W2^T + b2   (128 blocks x 64)
// ---------------------------------------------------------------------------
__global__ __launch_bounds__(64) void k_readout(
    const float* __restrict__ gr, const float* __restrict__ W1,
    const float* __restrict__ b1, const float* __restrict__ W2,
    const float* __restrict__ b2, float* __restrict__ out)
{
    const int g = blockIdx.x, j = threadIdx.x;
    float acc = b1[j];
    const float4* grow = (const float4*)&gr[g * HID];
    const float4* wrow = (const float4*)&W1[j * HID];
#pragma unroll
    for (int k4 = 0; k4 < 32; k4++) {
        float4 a = grow[k4], w = wrow[k4];
        acc += a.x * w.x + a.y * w.y + a.z * w.z + a.w * w.w;
    }
    float h = fmaxf(acc, 0.0f) * W2[j];
#pragma unroll
    for (int msk = 32; msk >= 1; msk >>= 1) h += __shfl_xor(h, msk);
    if (j == 0) out[g] = h + b2[0];
}

// ---------------------------------------------------------------------------
extern "C" void kernel_launch(void* const* d_in, const int* in_sizes, int n_in,
                              void* d_out, int out_size, void* d_ws, size_t ws_size,
                              hipStream_t stream)
{
    const float* nf    = (const float*)d_in[0];
    const int*   ei    = (const int*)d_in[1];
    const int*   batch = (const int*)d_in[2];
    const float* embW  = (const float*)d_in[3];
    const float* embb  = (const float*)d_in[4];
    const float* embg  = (const float*)d_in[5];
    const float* embbe = (const float*)d_in[6];
    const float* msgW  = (const float*)d_in[7];
    const float* msgb  = (const float*)d_in[8];
    const float* attW  = (const float*)d_in[9];
    const float* attb  = (const float*)d_in[10];
    const float* Wih   = (const float*)d_in[11];
    const float* bih   = (const float*)d_in[12];
    const float* Whh   = (const float*)d_in[13];
    const float* bhh   = (const float*)d_in[14];
    const float* bng   = (const float*)d_in[15];
    const float* bnb   = (const float*)d_in[16];
    const float* roW1  = (const float*)d_in[17];
    const float* rob1  = (const float*)d_in[18];
    const float* roW2  = (const float*)d_in[19];
    const float* rob2  = (const float*)d_in[20];
    const int* src = ei;
    const int* dst = ei + NE;
    float* out = (float*)d_out;

    // ---- workspace layout (all sections 16B-multiple) ----
    char* base = (char*)d_ws;
    const size_t NH = (size_t)NN * HID;      // 6.4M floats
    double* bnsum = (double*)base;           // 256 doubles = 2048 B
    float* x     = (float*)(base + 2048);
    float* y     = x + NH;
    float* aggx  = y + NH;
    float* as_   = aggx + NH;
    float* ad_   = as_ + NN;
    float* sumatt= ad_ + NN;
    float* ss    = sumatt + NN;              // 256: scale|shift
    float* gr    = ss + 256;                 // 128*128
    float* Wc    = gr + NGRAPHS * HID;       // 4*384*128 fp32
    float* bmih  = Wc + 4 * 384 * 128;       // 4*384
    int* rowptr  = (int*)(bmih + 4 * 384);   // NN+4 (padded for alignment)
    int* wptr    = rowptr + NN + 4;          // NN
    int* cnt     = wptr + NN;                // NN
    int* ssrc    = cnt + NN;                 // NE
    short* wcb   = (short*)(ssrc + NE);      // 4*49152 bf16, frag-ordered
    short* whhb  = wcb + 4 * 49152;          // 4*49152 bf16, frag-ordered

    // ---- once-per-call precompute: combined weights (+bf16 frags) + CSR ----
    k_wc<<<4 * 384, 128, 0, stream>>>(Wih, msgW, msgb, Wc, bmih);
    k_frag<<<8 * 192, 256, 0, stream>>>(Wc, Whh, wcb, whhb);
    hipMemsetAsync(cnt, 0, NN * sizeof(int), stream);
    k_count<<<(NE + 255) / 256, 256, 0, stream>>>(dst, cnt);
    k_scan<<<1, 1024, 0, stream>>>(cnt, rowptr, wptr);
    k_scatter<<<(NE + 255) / 256, 256, 0, stream>>>(src, dst, wptr, ssrc);

    // ---- embedding + BN + att-proj for layer 0 ----
    hipMemsetAsync(bnsum, 0, 256 * sizeof(double), stream);
    k_embed<<<NN / TN, 256, 0, stream>>>(nf, embW, embb, y, bnsum);
    k_bnfin<<<1, 128, 0, stream>>>(bnsum, embg, embbe, ss);
    k_bnx<<<NN / 4, 256, 0, stream>>>(y, ss, attW, x, as_, ad_);

    for (int l = 0; l < NLAYERS; l++) {
        k_gather<<<NN / 8, 256, 0, stream>>>(rowptr, ssrc, x, as_, ad_, attb, l, aggx, sumatt);
        hipMemsetAsync(bnsum, 0, 256 * sizeof(double), stream);
        k_gru<<<(NN + 63) / 64, 256, 0, stream>>>(
            aggx, sumatt, x,
            wcb + (size_t)l * 49152, bmih + (size_t)l * 384, bih + (size_t)l * 384,
            whhb + (size_t)l * 49152, bhh + (size_t)l * 384, y, bnsum);
        k_bnfin<<<1, 128, 0, stream>>>(bnsum, bng + (size_t)l * HID, bnb + (size_t)l * HID, ss);
        const float* attW_next = attW + (size_t)((l + 1 < NLAYERS) ? l + 1 : l) * 256;
        k_bnx<<<NN / 4, 256, 0, stream>>>(y, ss, attW_next, x, as_, ad_);
    }

    hipMemsetAsync(gr, 0, NGRAPHS * HID * sizeof(float), stream);
    k_pool<<<NN / 8, 256, 0, stream>>>(x, batch, gr);
    k_readout<<<NGRAPHS, 64, 0, stream>>>(gr, roW1, rob1, roW2, rob2, out);
}

// Round 4
// 968.814 us; speedup vs baseline: 6.1323x; 1.1706x over previous
//
#include <hip/hip_runtime.h>
#include <math.h>

#define NN 50000
#define NE 600000
#define ADIM 75
#define HID 128
#define NLAYERS 4
#define NGRAPHS 128
#define BN_EPS 1e-5f
#define TN 16   // nodes per block in tiled node kernels

typedef short bhalf8 __attribute__((ext_vector_type(8)));
typedef float floatx4 __attribute__((ext_vector_type(4)));

__device__ __forceinline__ float sigm(float v) { return 1.0f / (1.0f + __expf(-v)); }

// fp32 -> bf16 with round-to-nearest-even
__device__ __forceinline__ unsigned short f2bf(float f) {
    unsigned u = __builtin_bit_cast(unsigned, f);
    u = (u + 0x7FFFu + ((u >> 16) & 1u)) >> 16;
    return (unsigned short)u;
}
__device__ __forceinline__ float bf2f(unsigned short h) {
    return __builtin_bit_cast(float, ((unsigned)h) << 16);
}

// ---------------------------------------------------------------------------
// Embedding: y = relu(nf @ embW^T + embb), accumulate BN sums (double atomics)
// block 256 = 16 nodes x 16 f-groups; grid 3125
// ---------------------------------------------------------------------------
__global__ __launch_bounds__(256) void k_embed(
    const float* __restrict__ nf, const float* __restrict__ W,
    const float* __restrict__ b, float* __restrict__ y,
    double* __restrict__ bnsum)
{
    __shared__ float sNF[TN * 80];     // 75 padded to 80
    __shared__ float sW[128 * 76];     // 75 padded to 76
    __shared__ float sH[TN * 128];
    const int t = threadIdx.x;
    const int node0 = blockIdx.x * TN;

    for (int i = t; i < TN * ADIM; i += 256) {
        int r = i / ADIM, c = i - r * ADIM;
        sNF[r * 80 + c] = nf[node0 * ADIM + i];
    }
    for (int i = t; i < 128 * ADIM; i += 256) {
        int r = i / ADIM, c = i - r * ADIM;
        sW[r * 76 + c] = W[i];
    }
    __syncthreads();

    const int node = t >> 4, fg = t & 15;
    float acc[8];
#pragma unroll
    for (int j = 0; j < 8; j++) acc[j] = b[fg + 16 * j];

    const float* arow = &sNF[node * 80];
#pragma unroll 6
    for (int k = 0; k < 72; k += 4) {
        float4 a = *(const float4*)&arow[k];
#pragma unroll
        for (int j = 0; j < 8; j++) {
            float4 w = *(const float4*)&sW[(fg + 16 * j) * 76 + k];
            acc[j] += a.x * w.x + a.y * w.y + a.z * w.z + a.w * w.w;
        }
    }
    for (int k = 72; k < 75; k++) {
        float a = arow[k];
#pragma unroll
        for (int j = 0; j < 8; j++) acc[j] += a * sW[(fg + 16 * j) * 76 + k];
    }
#pragma unroll
    for (int j = 0; j < 8; j++) {
        float v = fmaxf(acc[j], 0.0f);
        int f = fg + 16 * j;
        sH[node * 128 + f] = v;
        y[(node0 + node) * HID + f] = v;
    }
    __syncthreads();
    if (t < 128) {
        float s = 0.f, s2 = 0.f;
#pragma unroll
        for (int n2 = 0; n2 < TN; n2++) { float v = sH[n2 * 128 + t]; s += v; s2 += v * v; }
        unsafeAtomicAdd(&bnsum[t], (double)s);
        unsafeAtomicAdd(&bnsum[128 + t], (double)s2);
    }
}

// ---------------------------------------------------------------------------
// BN finalize: scale/shift from double sums
// ---------------------------------------------------------------------------
__global__ void k_bnfin(const double* __restrict__ bnsum, const float* __restrict__ g,
                        const float* __restrict__ beta, float* __restrict__ ss)
{
    int f = threadIdx.x;
    double mean = bnsum[f] / (double)NN;
    double var  = bnsum[128 + f] / (double)NN - mean * mean;
    float inv = rsqrtf((float)var + BN_EPS);
    float sc = g[f] * inv;
    ss[f] = sc;
    ss[128 + f] = beta[f] - (float)mean * sc;
}

// ---------------------------------------------------------------------------
// Fused BN-apply + bf16 mirror + attention projections for the NEXT layer:
//   x = y*scale + shift ; xb = bf16(x) ; as_[n] = x.attW[:128] ; ad_ = x.attW[128:]
// block 256 = 4 nodes x 64 lanes (float2/lane); grid 12500
// ---------------------------------------------------------------------------
__global__ __launch_bounds__(256) void k_bnx(
    const float* __restrict__ y, const float* __restrict__ ss,
    const float* __restrict__ attW, float* __restrict__ x,
    unsigned short* __restrict__ xb,
    float* __restrict__ as_, float* __restrict__ ad_)
{
    const int t = threadIdx.x;
    const int n = blockIdx.x * 4 + (t >> 6);
    const int lane = t & 63;
    float2 sc = ((const float2*)ss)[lane];
    float2 sh = ((const float2*)(ss + 128))[lane];
    float2 v = ((const float2*)y)[(size_t)n * 64 + lane];
    float2 xv;
    xv.x = v.x * sc.x + sh.x;
    xv.y = v.y * sc.y + sh.y;
    ((float2*)x)[(size_t)n * 64 + lane] = xv;
    unsigned pk = (unsigned)f2bf(xv.x) | ((unsigned)f2bf(xv.y) << 16);
    ((unsigned*)xb)[(size_t)n * 64 + lane] = pk;
    float2 aws = ((const float2*)attW)[lane];
    float2 awd = ((const float2*)(attW + 128))[lane];
    float pas = xv.x * aws.x + xv.y * aws.y;
    float pad = xv.x * awd.x + xv.y * awd.y;
#pragma unroll
    for (int msk = 32; msk >= 1; msk >>= 1) {
        pas += __shfl_xor(pas, msk);
        pad += __shfl_xor(pad, msk);
    }
    if (lane == 0) { as_[n] = pas; ad_[n] = pad; }
}

// ---------------------------------------------------------------------------
// Combined-weight precompute: Wc[l] = Wih[l] @ Wm[l]  [384x128],
//                             bmih[l] = Wih[l] @ bm[l] [384]
// grid 4*384 blocks x 128 threads
// ---------------------------------------------------------------------------
__global__ __launch_bounds__(128) void k_wc(
    const float* __restrict__ Wih, const float* __restrict__ Wm,
    const float* __restrict__ bm, float* __restrict__ Wc, float* __restrict__ bmih)
{
    __shared__ float sw[128];
    __shared__ float red[128];
    const int b = blockIdx.x;
    const int l = b / 384, r = b - l * 384;
    const int t = threadIdx.x;
    const float* wihrow = Wih + ((size_t)l * 384 + r) * 128;
    sw[t] = wihrow[t];
    __syncthreads();
    const float* wm = Wm + (size_t)l * 128 * 128;
    float acc = 0.f;
#pragma unroll 8
    for (int k = 0; k < 128; k++) acc += sw[k] * wm[k * 128 + t];
    Wc[((size_t)l * 384 + r) * 128 + t] = acc;
    red[t] = sw[t] * bm[l * 128 + t];
    __syncthreads();
#pragma unroll
    for (int off = 64; off >= 1; off >>= 1) {
        if (t < off) red[t] += red[t + off];
        __syncthreads();
    }
    if (t == 0) bmih[l * 384 + r] = red[0];
}

// ---------------------------------------------------------------------------
// Convert Wc (fp32, [L][384][128]) and Whh to bf16 in MFMA B-fragment order:
//   layout [gate(3)][tc(8)][kb(4)][quad(4)][n(16)][j(8)] per layer-matrix
//   element = W[gate*128 + tc*16 + n][kb*32 + quad*8 + j]
// grid 8 mats * 192 blocks x 256 threads
// ---------------------------------------------------------------------------
__global__ __launch_bounds__(256) void k_frag(
    const float* __restrict__ Wc, const float* __restrict__ Whh,
    unsigned short* __restrict__ wcb, unsigned short* __restrict__ whhb)
{
    const int b = blockIdx.x;
    const int mat = b / 192;
    const int e = (b - mat * 192) * 256 + threadIdx.x;   // 0..49151
    const int l = mat >> 1, which = mat & 1;
    const float* src = which ? (Whh + (size_t)l * 49152) : (Wc + (size_t)l * 49152);
    unsigned short* dst = which ? (whhb + (size_t)l * 49152) : (wcb + (size_t)l * 49152);
    int j = e & 7, n = (e >> 3) & 15, quad = (e >> 7) & 3;
    int kb = (e >> 9) & 3, tc = (e >> 11) & 7, g = (e >> 14) & 3;
    int row = g * 128 + tc * 16 + n;
    int kk = kb * 32 + quad * 8 + j;
    dst[e] = f2bf(src[row * 128 + kk]);
}

// ---------------------------------------------------------------------------
// CSR build: histogram, single-block scan, scatter
// ---------------------------------------------------------------------------
__global__ __launch_bounds__(256) void k_count(const int* __restrict__ dst, int* __restrict__ cnt)
{
    int e = blockIdx.x * 256 + threadIdx.x;
    if (e < NE) atomicAdd(&cnt[dst[e]], 1);
}

__global__ __launch_bounds__(1024) void k_scan(
    const int* __restrict__ cnt, int* __restrict__ rowptr, int* __restrict__ wptr)
{
    __shared__ int s[1024];
    const int t = threadIdx.x;
    const int CH = 49;                       // 1024*49 >= 50000
    int begin = t * CH;
    int end = begin + CH; if (end > NN) end = NN;
    int sum = 0;
    for (int i = begin; i < end; i++) sum += cnt[i];
    s[t] = sum;
    __syncthreads();
    for (int off = 1; off < 1024; off <<= 1) {
        int v = (t >= off) ? s[t - off] : 0;
        __syncthreads();
        s[t] += v;
        __syncthreads();
    }
    int run = s[t] - sum;                    // exclusive prefix of this chunk
    for (int i = begin; i < end; i++) {
        rowptr[i] = run; wptr[i] = run;
        run += cnt[i];
    }
    if (t == 1023) rowptr[NN] = s[1023];
}

__global__ __launch_bounds__(256) void k_scatter(
    const int* __restrict__ src, const int* __restrict__ dst,
    int* __restrict__ wptr, int* __restrict__ ssrc)
{
    int e = blockIdx.x * 256 + threadIdx.x;
    if (e < NE) {
        int d = dst[e];
        int pos = atomicAdd(&wptr[d], 1);
        ssrc[pos] = src[e];
    }
}

// ---------------------------------------------------------------------------
// Gather-aggregate over bf16 x-table (no atomics): per node d,
//   aggxb[d] = bf16( sum_e att_e * xb[src_e] ) ; sumatt[d] = sum_e att_e
// att_e = sigmoid(as_[s] + ad_[d] + attb[l])
// block 256 = 8 nodes x 32 lanes (ushort4 = 4 feats/lane); grid 6250
// ---------------------------------------------------------------------------
__global__ __launch_bounds__(256) void k_gather(
    const int* __restrict__ rowptr, const int* __restrict__ ssrc,
    const unsigned short* __restrict__ xb, const float* __restrict__ as_,
    const float* __restrict__ ad_, const float* __restrict__ attb, int l,
    unsigned short* __restrict__ aggxb, float* __restrict__ sumatt)
{
    const int t = threadIdx.x;
    const int n = blockIdx.x * 8 + (t >> 5);
    const int lane = t & 31;
    const int r0 = rowptr[n], r1 = rowptr[n + 1];
    const float adv = ad_[n] + attb[l];
    float4 acc = make_float4(0.f, 0.f, 0.f, 0.f);
    float satt = 0.f;
    for (int i = r0; i < r1; i++) {
        int s = ssrc[i];
        float att = sigm(as_[s] + adv);
        ushort4 v = ((const ushort4*)xb)[(size_t)s * 32 + lane];
        acc.x += bf2f(v.x) * att; acc.y += bf2f(v.y) * att;
        acc.z += bf2f(v.z) * att; acc.w += bf2f(v.w) * att;
        satt += att;
    }
    ushort4 o;
    o.x = f2bf(acc.x); o.y = f2bf(acc.y); o.z = f2bf(acc.z); o.w = f2bf(acc.w);
    ((ushort4*)aggxb)[(size_t)n * 32 + lane] = o;
    if (lane == 0) sumatt[n] = satt;
}

// ---------------------------------------------------------------------------
// MFMA GRU: gi = aggx@Wc^T + sumatt*bmih + bih ; gh = x@Whh^T + bhh
//           gates, h_new, BN sums.
// block 256 = 4 waves x 16 nodes each (64 nodes/block); grid 782.
// 6 rounds: (Wc,Whh) x gates (r,n,z). W chunks (32KB bf16, frag-ordered)
// streamed via global_load_lds width=16. A-frags: plain bf16 16B loads.
// C/D layout: col=lane&15 (output f within 16-tile), row=quad*4+reg (node).
// ---------------------------------------------------------------------------
#define LOADW(PTR)                                                            \
    __syncthreads();                                                          \
    _Pragma("unroll")                                                         \
    for (int i = 0; i < 8; i++) {                                             \
        const unsigned short* gp = (PTR) + ((wave * 8 + i) * 64 + lane) * 8;  \
        short* lp = sW + (wave * 8 + i) * 512;                                \
        __builtin_amdgcn_global_load_lds(                                     \
            (__attribute__((address_space(1))) void*)gp,                      \
            (__attribute__((address_space(3))) void*)lp, 16, 0, 0);           \
    }                                                                         \
    __syncthreads();

#define MM(AF, ACC)                                                           \
    _Pragma("unroll")                                                         \
    for (int tc = 0; tc < 8; tc++) {                                          \
        _Pragma("unroll")                                                     \
        for (int kb = 0; kb < 4; kb++) {                                      \
            bhalf8 bf = *(const bhalf8*)&sW[(((tc * 4 + kb) * 4 + quad) * 16 + col) * 8]; \
            ACC[tc] = __builtin_amdgcn_mfma_f32_16x16x32_bf16(AF[kb], bf, ACC[tc], 0, 0, 0); \
        }                                                                     \
    }

__global__ __launch_bounds__(256) void k_gru(
    const unsigned short* __restrict__ aggxb, const float* __restrict__ sumatt,
    const unsigned short* __restrict__ xb, const float* __restrict__ x,
    const unsigned short* __restrict__ wcb, const float* __restrict__ bmih,
    const float* __restrict__ bih,
    const unsigned short* __restrict__ whhb, const float* __restrict__ bhh,
    float* __restrict__ y, double* __restrict__ bnsum)
{
    __shared__ __align__(16) short sW[128 * 128];   // 32 KB; reused as h-stage fp32
    const int t = threadIdx.x;
    const int wave = t >> 6, lane = t & 63;
    const int col = lane & 15, quad = (lane >> 4) & 3;
    const int node0 = blockIdx.x * 64;

    // ---- A-fragments: direct bf16 16B loads, A[m=lane&15][k=quad*8+j] ----
    const int anode = node0 + wave * 16 + col;
    bhalf8 afA[4], afX[4];
#pragma unroll
    for (int kb = 0; kb < 4; kb++) {
        afA[kb] = *(const bhalf8*)&aggxb[(size_t)anode * HID + kb * 32 + quad * 8];
        afX[kb] = *(const bhalf8*)&xb[(size_t)anode * HID + kb * 32 + quad * 8];
    }
    float sa[4];
#pragma unroll
    for (int e = 0; e < 4; e++) sa[e] = sumatt[node0 + wave * 16 + quad * 4 + e];

    floatx4 acc_i[8], acc_h[8], gr_[8], gn_[8];

    // ================= gate r (g=0) =================
#pragma unroll
    for (int tc = 0; tc < 8; tc++) {
        int f = 0 * 128 + tc * 16 + col;
        float bi = bih[f], bm = bmih[f], bh = bhh[f];
        acc_i[tc] = (floatx4){bi + sa[0] * bm, bi + sa[1] * bm, bi + sa[2] * bm, bi + sa[3] * bm};
        acc_h[tc] = (floatx4){bh, bh, bh, bh};
    }
    LOADW(wcb + 0 * 16384); MM(afA, acc_i);
    LOADW(whhb + 0 * 16384); MM(afX, acc_h);
#pragma unroll
    for (int tc = 0; tc < 8; tc++)
#pragma unroll
        for (int e = 0; e < 4; e++)
            gr_[tc][e] = sigm(acc_i[tc][e] + acc_h[tc][e]);

    // ================= gate n (g=2) =================
#pragma unroll
    for (int tc = 0; tc < 8; tc++) {
        int f = 2 * 128 + tc * 16 + col;
        float bi = bih[f], bm = bmih[f], bh = bhh[f];
        acc_i[tc] = (floatx4){bi + sa[0] * bm, bi + sa[1] * bm, bi + sa[2] * bm, bi + sa[3] * bm};
        acc_h[tc] = (floatx4){bh, bh, bh, bh};
    }
    LOADW(wcb + 2 * 16384); MM(afA, acc_i);
    LOADW(whhb + 2 * 16384); MM(afX, acc_h);
#pragma unroll
    for (int tc = 0; tc < 8; tc++)
#pragma unroll
        for (int e = 0; e < 4; e++)
            gn_[tc][e] = tanhf(acc_i[tc][e] + gr_[tc][e] * acc_h[tc][e]);

    // ================= gate z (g=1) + h =================
#pragma unroll
    for (int tc = 0; tc < 8; tc++) {
        int f = 1 * 128 + tc * 16 + col;
        float bi = bih[f], bm = bmih[f], bh = bhh[f];
        acc_i[tc] = (floatx4){bi + sa[0] * bm, bi + sa[1] * bm, bi + sa[2] * bm, bi + sa[3] * bm};
        acc_h[tc] = (floatx4){bh, bh, bh, bh};
    }
    LOADW(wcb + 1 * 16384); MM(afA, acc_i);
    LOADW(whhb + 1 * 16384); MM(afX, acc_h);

    __syncthreads();                          // done reading sW as weights
    float* hst = (float*)sW;                  // 64 x 128 fp32 = 32 KB
#pragma unroll
    for (int tc = 0; tc < 8; tc++) {
#pragma unroll
        for (int e = 0; e < 4; e++) {
            float z = sigm(acc_i[tc][e] + acc_h[tc][e]);
            int nd = node0 + wave * 16 + quad * 4 + e;
            float xv = x[(size_t)nd * HID + tc * 16 + col];
            float h = (1.0f - z) * gn_[tc][e] + z * xv;
            hst[(wave * 16 + quad * 4 + e) * 128 + tc * 16 + col] = h;
        }
    }
    __syncthreads();

    // coalesced y write
#pragma unroll
    for (int i = 0; i < 32; i++) {
        int idx = t + i * 256;
        if (node0 + (idx >> 7) < NN) y[(size_t)node0 * HID + idx] = hst[idx];
    }
    // BN partial sums
    if (t < 128) {
        int count = NN - node0; if (count > 64) count = 64;
        float s = 0.f, s2 = 0.f;
        for (int m = 0; m < count; m++) { float v = hst[m * 128 + t]; s += v; s2 += v * v; }
        unsafeAtomicAdd(&bnsum[t], (double)s);
        unsafeAtomicAdd(&bnsum[128 + t], (double)s2);
    }
}

// ---------------------------------------------------------------------------
// Segmented sum-pool (batch_idx is SORTED): block = 256 threads covering a
// 256-node chunk; thread t owns feature f=t&127 of stream s=t>>7 (even/odd
// nodes interleaved). Register-accumulate, flush one atomic per graph
// boundary (~1-2 per chunk). grid 196.
// ---------------------------------------------------------------------------
__global__ __launch_bounds__(256) void k_pool(
    const float* __restrict__ x, const int* __restrict__ batch, float* __restrict__ gr)
{
    __shared__ int sb[256];
    const int t = threadIdx.x;
    const int nb = blockIdx.x * 256;
    int ld = nb + t; if (ld >= NN) ld = NN - 1;
    sb[t] = batch[ld];
    __syncthreads();
    const int s = t >> 7, f = t & 127;
    float acc = 0.f; int cur = -1;
    for (int i = s; i < 256; i += 2) {
        int n = nb + i;
        if (n >= NN) break;
        int g = sb[i];
        if (g != cur) {
            if (cur >= 0) unsafeAtomicAdd(&gr[(size_t)cur * HID + f], acc);
            acc = 0.f; cur = g;
        }
        acc += x[(size_t)n * HID + f];
    }
    if (cur >= 0) unsafeAtomicAdd(&gr[(size_t)cur * HID + f], acc);
}

// ---------------------------------------------------------------------------
// Readout: out[g] = relu(gr[g] @ W1^T + b1) @ W2^T + b2   (128 blocks x 64)
// ---------------------------------------------------------------------------
__global__ __launch_bounds__(64) void k_readout(
    const float* __restrict__ gr, const float* __restrict__ W1,
    const float* __restrict__ b1, const float* __restrict__ W2,
    const float* __restrict__ b2, float* __restrict__ out)
{
    const int g = blockIdx.x, j = threadIdx.x;
    float acc = b1[j];
    const float4* grow = (const float4*)&gr[g * HID];
    const float4* wrow = (const float4*)&W1[j * HID];
#pragma unroll
    for (int k4 = 0; k4 < 32; k4++) {
        float4 a = grow[k4], w = wrow[k4];
        acc += a.x * w.x + a.y * w.y + a.z * w.z + a.w * w.w;
    }
    float h = fmaxf(acc, 0.0f) * W2[j];
#pragma unroll
    for (int msk = 32; msk >= 1; msk >>= 1) h += __shfl_xor(h, msk);
    if (j == 0) out[g] = h + b2[0];
}

// ---------------------------------------------------------------------------
extern "C" void kernel_launch(void* const* d_in, const int* in_sizes, int n_in,
                              void* d_out, int out_size, void* d_ws, size_t ws_size,
                              hipStream_t stream)
{
    const float* nf    = (const float*)d_in[0];
    const int*   ei    = (const int*)d_in[1];
    const int*   batch = (const int*)d_in[2];
    const float* embW  = (const float*)d_in[3];
    const float* embb  = (const float*)d_in[4];
    const float* embg  = (const float*)d_in[5];
    const float* embbe = (const float*)d_in[6];
    const float* msgW  = (const float*)d_in[7];
    const float* msgb  = (const float*)d_in[8];
    const float* attW  = (const float*)d_in[9];
    const float* attb  = (const float*)d_in[10];
    const float* Wih   = (const float*)d_in[11];
    const float* bih   = (const float*)d_in[12];
    const float* Whh   = (const float*)d_in[13];
    const float* bhh   = (const float*)d_in[14];
    const float* bng   = (const float*)d_in[15];
    const float* bnb   = (const float*)d_in[16];
    const float* roW1  = (const float*)d_in[17];
    const float* rob1  = (const float*)d_in[18];
    const float* roW2  = (const float*)d_in[19];
    const float* rob2  = (const float*)d_in[20];
    const int* src = ei;
    const int* dst = ei + NE;
    float* out = (float*)d_out;

    // ---- workspace layout (all sections 16B-multiple) ----
    char* base = (char*)d_ws;
    const size_t NH = (size_t)NN * HID;      // 6.4M elements
    double* bnsum = (double*)base;           // 256 doubles = 2048 B
    float* x     = (float*)(base + 2048);    // fp32 node state
    float* y     = x + NH;                   // pre-BN state
    unsigned short* xb    = (unsigned short*)(y + NH);   // bf16 mirror of x
    unsigned short* aggxb = xb + NH;                     // bf16 gather output
    float* as_   = (float*)(aggxb + NH);
    float* ad_   = as_ + NN;
    float* sumatt= ad_ + NN;
    float* ss    = sumatt + NN;              // 256: scale|shift
    float* gr    = ss + 256;                 // 128*128
    float* Wc    = gr + NGRAPHS * HID;       // 4*384*128 fp32
    float* bmih  = Wc + 4 * 384 * 128;       // 4*384
    int* rowptr  = (int*)(bmih + 4 * 384);   // NN+4 (padded for alignment)
    int* wptr    = rowptr + NN + 4;          // NN
    int* cnt     = wptr + NN;                // NN
    int* ssrc    = cnt + NN;                 // NE
    unsigned short* wcb  = (unsigned short*)(ssrc + NE); // 4*49152 bf16 frags
    unsigned short* whhb = wcb + 4 * 49152;              // 4*49152 bf16 frags

    // ---- once-per-call precompute: combined weights (+bf16 frags) + CSR ----
    k_wc<<<4 * 384, 128, 0, stream>>>(Wih, msgW, msgb, Wc, bmih);
    k_frag<<<8 * 192, 256, 0, stream>>>(Wc, Whh, wcb, whhb);
    hipMemsetAsync(cnt, 0, NN * sizeof(int), stream);
    k_count<<<(NE + 255) / 256, 256, 0, stream>>>(dst, cnt);
    k_scan<<<1, 1024, 0, stream>>>(cnt, rowptr, wptr);
    k_scatter<<<(NE + 255) / 256, 256, 0, stream>>>(src, dst, wptr, ssrc);

    // ---- embedding + BN + att-proj for layer 0 ----
    hipMemsetAsync(bnsum, 0, 256 * sizeof(double), stream);
    k_embed<<<NN / TN, 256, 0, stream>>>(nf, embW, embb, y, bnsum);
    k_bnfin<<<1, 128, 0, stream>>>(bnsum, embg, embbe, ss);
    k_bnx<<<NN / 4, 256, 0, stream>>>(y, ss, attW, x, xb, as_, ad_);

    for (int l = 0; l < NLAYERS; l++) {
        k_gather<<<NN / 8, 256, 0, stream>>>(rowptr, ssrc, xb, as_, ad_, attb, l, aggxb, sumatt);
        hipMemsetAsync(bnsum, 0, 256 * sizeof(double), stream);
        k_gru<<<(NN + 63) / 64, 256, 0, stream>>>(
            aggxb, sumatt, xb, x,
            wcb + (size_t)l * 49152, bmih + (size_t)l * 384, bih + (size_t)l * 384,
            whhb + (size_t)l * 49152, bhh + (size_t)l * 384, y, bnsum);
        k_bnfin<<<1, 128, 0, stream>>>(bnsum, bng + (size_t)l * HID, bnb + (size_t)l * HID, ss);
        const float* attW_next = attW + (size_t)((l + 1 < NLAYERS) ? l + 1 : l) * 256;
        k_bnx<<<NN / 4, 256, 0, stream>>>(y, ss, attW_next, x, xb, as_, ad_);
    }

    hipMemsetAsync(gr, 0, NGRAPHS * HID * sizeof(float), stream);
    k_pool<<<(NN + 255) / 256, 256, 0, stream>>>(x, batch, gr);
    k_readout<<<NGRAPHS, 64, 0, stream>>>(gr, roW1, rob1, roW2, rob2, out);
}

// Round 5
// 823.771 us; speedup vs baseline: 7.2121x; 1.1761x over previous
//
#include <hip/hip_runtime.h>
#include <math.h>

#define NN 50000
#define NE 600000
#define ADIM 75
#define HID 128
#define NLAYERS 4
#define NGRAPHS 128
#define BN_EPS 1e-5f
#define TN 16   // nodes per block in tiled node kernels

typedef short bhalf8 __attribute__((ext_vector_type(8)));
typedef float floatx4 __attribute__((ext_vector_type(4)));

__device__ __forceinline__ float sigm(float v) { return 1.0f / (1.0f + __expf(-v)); }

// fp32 -> bf16 with round-to-nearest-even
__device__ __forceinline__ unsigned short f2bf(float f) {
    unsigned u = __builtin_bit_cast(unsigned, f);
    u = (u + 0x7FFFu + ((u >> 16) & 1u)) >> 16;
    return (unsigned short)u;
}
__device__ __forceinline__ float bf2f(unsigned short h) {
    return __builtin_bit_cast(float, ((unsigned)h) << 16);
}

// ---------------------------------------------------------------------------
// Embedding: y = relu(nf @ embW^T + embb), accumulate BN sums (double atomics)
// block 256 = 16 nodes x 16 f-groups; grid 3125
// ---------------------------------------------------------------------------
__global__ __launch_bounds__(256) void k_embed(
    const float* __restrict__ nf, const float* __restrict__ W,
    const float* __restrict__ b, float* __restrict__ y,
    double* __restrict__ bnsum)
{
    __shared__ float sNF[TN * 80];     // 75 padded to 80
    __shared__ float sW[128 * 76];     // 75 padded to 76
    __shared__ float sH[TN * 128];
    const int t = threadIdx.x;
    const int node0 = blockIdx.x * TN;

    for (int i = t; i < TN * ADIM; i += 256) {
        int r = i / ADIM, c = i - r * ADIM;
        sNF[r * 80 + c] = nf[node0 * ADIM + i];
    }
    for (int i = t; i < 128 * ADIM; i += 256) {
        int r = i / ADIM, c = i - r * ADIM;
        sW[r * 76 + c] = W[i];
    }
    __syncthreads();

    const int node = t >> 4, fg = t & 15;
    float acc[8];
#pragma unroll
    for (int j = 0; j < 8; j++) acc[j] = b[fg + 16 * j];

    const float* arow = &sNF[node * 80];
#pragma unroll 6
    for (int k = 0; k < 72; k += 4) {
        float4 a = *(const float4*)&arow[k];
#pragma unroll
        for (int j = 0; j < 8; j++) {
            float4 w = *(const float4*)&sW[(fg + 16 * j) * 76 + k];
            acc[j] += a.x * w.x + a.y * w.y + a.z * w.z + a.w * w.w;
        }
    }
    for (int k = 72; k < 75; k++) {
        float a = arow[k];
#pragma unroll
        for (int j = 0; j < 8; j++) acc[j] += a * sW[(fg + 16 * j) * 76 + k];
    }
#pragma unroll
    for (int j = 0; j < 8; j++) {
        float v = fmaxf(acc[j], 0.0f);
        int f = fg + 16 * j;
        sH[node * 128 + f] = v;
        y[(node0 + node) * HID + f] = v;
    }
    __syncthreads();
    if (t < 128) {
        float s = 0.f, s2 = 0.f;
#pragma unroll
        for (int n2 = 0; n2 < TN; n2++) { float v = sH[n2 * 128 + t]; s += v; s2 += v * v; }
        unsafeAtomicAdd(&bnsum[t], (double)s);
        unsafeAtomicAdd(&bnsum[128 + t], (double)s2);
    }
}

// ---------------------------------------------------------------------------
// BN finalize: scale/shift from double sums
// ---------------------------------------------------------------------------
__global__ void k_bnfin(const double* __restrict__ bnsum, const float* __restrict__ g,
                        const float* __restrict__ beta, float* __restrict__ ss)
{
    int f = threadIdx.x;
    double mean = bnsum[f] / (double)NN;
    double var  = bnsum[128 + f] / (double)NN - mean * mean;
    float inv = rsqrtf((float)var + BN_EPS);
    float sc = g[f] * inv;
    ss[f] = sc;
    ss[128 + f] = beta[f] - (float)mean * sc;
}

// ---------------------------------------------------------------------------
// Fused BN-apply + bf16 mirror + attention projections for the NEXT layer:
//   x = y*scale + shift ; xb = bf16(x) ; as_[n] = x.attW[:128] ; ad_ = x.attW[128:]
// block 256 = 4 nodes x 64 lanes (float2/lane); grid 12500
// ---------------------------------------------------------------------------
__global__ __launch_bounds__(256) void k_bnx(
    const float* __restrict__ y, const float* __restrict__ ss,
    const float* __restrict__ attW, float* __restrict__ x,
    unsigned short* __restrict__ xb,
    float* __restrict__ as_, float* __restrict__ ad_)
{
    const int t = threadIdx.x;
    const int n = blockIdx.x * 4 + (t >> 6);
    const int lane = t & 63;
    float2 sc = ((const float2*)ss)[lane];
    float2 sh = ((const float2*)(ss + 128))[lane];
    float2 v = ((const float2*)y)[(size_t)n * 64 + lane];
    float2 xv;
    xv.x = v.x * sc.x + sh.x;
    xv.y = v.y * sc.y + sh.y;
    ((float2*)x)[(size_t)n * 64 + lane] = xv;
    unsigned pk = (unsigned)f2bf(xv.x) | ((unsigned)f2bf(xv.y) << 16);
    ((unsigned*)xb)[(size_t)n * 64 + lane] = pk;
    float2 aws = ((const float2*)attW)[lane];
    float2 awd = ((const float2*)(attW + 128))[lane];
    float pas = xv.x * aws.x + xv.y * aws.y;
    float pad = xv.x * awd.x + xv.y * awd.y;
#pragma unroll
    for (int msk = 32; msk >= 1; msk >>= 1) {
        pas += __shfl_xor(pas, msk);
        pad += __shfl_xor(pad, msk);
    }
    if (lane == 0) { as_[n] = pas; ad_[n] = pad; }
}

// ---------------------------------------------------------------------------
// Combined-weight precompute: Wc[l] = Wih[l] @ Wm[l]  [384x128],
//                             bmih[l] = Wih[l] @ bm[l] [384]
// grid 4*384 blocks x 128 threads
// ---------------------------------------------------------------------------
__global__ __launch_bounds__(128) void k_wc(
    const float* __restrict__ Wih, const float* __restrict__ Wm,
    const float* __restrict__ bm, float* __restrict__ Wc, float* __restrict__ bmih)
{
    __shared__ float sw[128];
    __shared__ float red[128];
    const int b = blockIdx.x;
    const int l = b / 384, r = b - l * 384;
    const int t = threadIdx.x;
    const float* wihrow = Wih + ((size_t)l * 384 + r) * 128;
    sw[t] = wihrow[t];
    __syncthreads();
    const float* wm = Wm + (size_t)l * 128 * 128;
    float acc = 0.f;
#pragma unroll 8
    for (int k = 0; k < 128; k++) acc += sw[k] * wm[k * 128 + t];
    Wc[((size_t)l * 384 + r) * 128 + t] = acc;
    red[t] = sw[t] * bm[l * 128 + t];
    __syncthreads();
#pragma unroll
    for (int off = 64; off >= 1; off >>= 1) {
        if (t < off) red[t] += red[t + off];
        __syncthreads();
    }
    if (t == 0) bmih[l * 384 + r] = red[0];
}

// ---------------------------------------------------------------------------
// Convert Wc (fp32, [L][384][128]) and Whh to bf16 in MFMA B-fragment order:
//   layout [gate(3)][tc(8)][kb(4)][quad(4)][n(16)][j(8)] per layer-matrix
//   element = W[gate*128 + tc*16 + n][kb*32 + quad*8 + j]
// grid 8 mats * 192 blocks x 256 threads
// ---------------------------------------------------------------------------
__global__ __launch_bounds__(256) void k_frag(
    const float* __restrict__ Wc, const float* __restrict__ Whh,
    unsigned short* __restrict__ wcb, unsigned short* __restrict__ whhb)
{
    const int b = blockIdx.x;
    const int mat = b / 192;
    const int e = (b - mat * 192) * 256 + threadIdx.x;   // 0..49151
    const int l = mat >> 1, which = mat & 1;
    const float* src = which ? (Whh + (size_t)l * 49152) : (Wc + (size_t)l * 49152);
    unsigned short* dst = which ? (whhb + (size_t)l * 49152) : (wcb + (size_t)l * 49152);
    int j = e & 7, n = (e >> 3) & 15, quad = (e >> 7) & 3;
    int kb = (e >> 9) & 3, tc = (e >> 11) & 7, g = (e >> 14) & 3;
    int row = g * 128 + tc * 16 + n;
    int kk = kb * 32 + quad * 8 + j;
    dst[e] = f2bf(src[row * 128 + kk]);
}

// ---------------------------------------------------------------------------
// CSR build: histogram, 3-kernel device-wide scan, scatter
// ---------------------------------------------------------------------------
__global__ __launch_bounds__(256) void k_count(const int* __restrict__ dst, int* __restrict__ cnt)
{
    int e = blockIdx.x * 256 + threadIdx.x;
    if (e < NE) atomicAdd(&cnt[dst[e]], 1);
}

#define SCAN_B 512
#define SCAN_G 98          // 98*512 = 50176 >= 50000

// stage 1: intra-block exclusive scan of cnt -> rowptr (local), block totals
__global__ __launch_bounds__(SCAN_B) void k_scan1(
    const int* __restrict__ cnt, int* __restrict__ rowptr, int* __restrict__ bsum)
{
    __shared__ int s[SCAN_B];
    const int t = threadIdx.x;
    const int i = blockIdx.x * SCAN_B + t;
    int v = (i < NN) ? cnt[i] : 0;
    s[t] = v;
    __syncthreads();
#pragma unroll
    for (int off = 1; off < SCAN_B; off <<= 1) {
        int u = (t >= off) ? s[t - off] : 0;
        __syncthreads();
        s[t] += u;
        __syncthreads();
    }
    if (i < NN) rowptr[i] = s[t] - v;        // local exclusive
    if (t == SCAN_B - 1) bsum[blockIdx.x] = s[t];
}

// stage 2: exclusive scan of the 98 block totals (one small block)
__global__ __launch_bounds__(128) void k_scan2(int* __restrict__ bsum, int* __restrict__ rowptr)
{
    __shared__ int s[128];
    const int t = threadIdx.x;
    int v = (t < SCAN_G) ? bsum[t] : 0;
    s[t] = v;
    __syncthreads();
#pragma unroll
    for (int off = 1; off < 128; off <<= 1) {
        int u = (t >= off) ? s[t - off] : 0;
        __syncthreads();
        s[t] += u;
        __syncthreads();
    }
    if (t < SCAN_G) bsum[t] = s[t] - v;      // exclusive offsets
    if (t == 127) rowptr[NN] = s[127];       // grand total (= NE)
}

// stage 3: add block offsets; emit wptr copy
__global__ __launch_bounds__(SCAN_B) void k_scan3(
    int* __restrict__ rowptr, const int* __restrict__ bsum, int* __restrict__ wptr)
{
    const int i = blockIdx.x * SCAN_B + threadIdx.x;
    if (i < NN) {
        int v = rowptr[i] + bsum[blockIdx.x];
        rowptr[i] = v;
        wptr[i] = v;
    }
}

__global__ __launch_bounds__(256) void k_scatter(
    const int* __restrict__ src, const int* __restrict__ dst,
    int* __restrict__ wptr, int* __restrict__ ssrc)
{
    int e = blockIdx.x * 256 + threadIdx.x;
    if (e < NE) {
        int d = dst[e];
        int pos = atomicAdd(&wptr[d], 1);
        ssrc[pos] = src[e];
    }
}

// ---------------------------------------------------------------------------
// Gather-aggregate over bf16 x-table (no atomics), software-pipelined:
//   aggxb[d] = bf16( sum_e att_e * xb[src_e] ) ; sumatt[d] = sum_e att_e
// att_e = sigmoid(as_[s] + ad_[d] + attb[l])
// block 256 = 8 nodes x 32 lanes (ushort4 = 4 feats/lane); grid 6250
// ---------------------------------------------------------------------------
__global__ __launch_bounds__(256) void k_gather(
    const int* __restrict__ rowptr, const int* __restrict__ ssrc,
    const unsigned short* __restrict__ xb, const float* __restrict__ as_,
    const float* __restrict__ ad_, const float* __restrict__ attb, int l,
    unsigned short* __restrict__ aggxb, float* __restrict__ sumatt)
{
    const int t = threadIdx.x;
    const int n = blockIdx.x * 8 + (t >> 5);
    const int lane = t & 31;
    const int r0 = rowptr[n], r1 = rowptr[n + 1];
    const float adv = ad_[n] + attb[l];
    float4 acc = make_float4(0.f, 0.f, 0.f, 0.f);
    float satt = 0.f;
    if (r0 < r1) {
        int s = ssrc[r0];
        ushort4 v = ((const ushort4*)xb)[(size_t)s * 32 + lane];
        float a = as_[s];
        for (int i = r0; i < r1; i++) {
            // prefetch edge i+1 while computing edge i
            int s2 = (i + 1 < r1) ? ssrc[i + 1] : s;
            ushort4 v2 = ((const ushort4*)xb)[(size_t)s2 * 32 + lane];
            float a2 = as_[s2];
            float att = sigm(a + adv);
            acc.x += bf2f(v.x) * att; acc.y += bf2f(v.y) * att;
            acc.z += bf2f(v.z) * att; acc.w += bf2f(v.w) * att;
            satt += att;
            v = v2; a = a2;
        }
    }
    ushort4 o;
    o.x = f2bf(acc.x); o.y = f2bf(acc.y); o.z = f2bf(acc.z); o.w = f2bf(acc.w);
    ((ushort4*)aggxb)[(size_t)n * 32 + lane] = o;
    if (lane == 0) sumatt[n] = satt;
}

// ---------------------------------------------------------------------------
// MFMA GRU: gi = aggx@Wc^T + sumatt*bmih + bih ; gh = x@Whh^T + bhh
//           gates, h_new, BN sums.
// block 256 = 4 waves x 16 nodes each (64 nodes/block); grid 782.
// 6 rounds: (Wc,Whh) x gates (r,n,z). W chunks (32KB bf16, frag-ordered)
// streamed via global_load_lds width=16. A-frags: plain bf16 16B loads.
// C/D layout: col=lane&15 (output f within 16-tile), row=quad*4+reg (node).
// ---------------------------------------------------------------------------
#define LOADW(PTR)                                                            \
    __syncthreads();                                                          \
    _Pragma("unroll")                                                         \
    for (int i = 0; i < 8; i++) {                                             \
        const unsigned short* gp = (PTR) + ((wave * 8 + i) * 64 + lane) * 8;  \
        short* lp = sW + (wave * 8 + i) * 512;                                \
        __builtin_amdgcn_global_load_lds(                                     \
            (__attribute__((address_space(1))) void*)gp,                      \
            (__attribute__((address_space(3))) void*)lp, 16, 0, 0);           \
    }                                                                         \
    __syncthreads();

#define MM(AF, ACC)                                                           \
    _Pragma("unroll")                                                         \
    for (int tc = 0; tc < 8; tc++) {                                          \
        _Pragma("unroll")                                                     \
        for (int kb = 0; kb < 4; kb++) {                                      \
            bhalf8 bf = *(const bhalf8*)&sW[(((tc * 4 + kb) * 4 + quad) * 16 + col) * 8]; \
            ACC[tc] = __builtin_amdgcn_mfma_f32_16x16x32_bf16(AF[kb], bf, ACC[tc], 0, 0, 0); \
        }                                                                     \
    }

__global__ __launch_bounds__(256) void k_gru(
    const unsigned short* __restrict__ aggxb, const float* __restrict__ sumatt,
    const unsigned short* __restrict__ xb, const float* __restrict__ x,
    const unsigned short* __restrict__ wcb, const float* __restrict__ bmih,
    const float* __restrict__ bih,
    const unsigned short* __restrict__ whhb, const float* __restrict__ bhh,
    float* __restrict__ y, double* __restrict__ bnsum)
{
    __shared__ __align__(16) short sW[128 * 128];   // 32 KB; reused as h-stage fp32
    const int t = threadIdx.x;
    const int wave = t >> 6, lane = t & 63;
    const int col = lane & 15, quad = (lane >> 4) & 3;
    const int node0 = blockIdx.x * 64;

    // ---- A-fragments: direct bf16 16B loads, A[m=lane&15][k=quad*8+j] ----
    const int anode = node0 + wave * 16 + col;
    bhalf8 afA[4], afX[4];
#pragma unroll
    for (int kb = 0; kb < 4; kb++) {
        afA[kb] = *(const bhalf8*)&aggxb[(size_t)anode * HID + kb * 32 + quad * 8];
        afX[kb] = *(const bhalf8*)&xb[(size_t)anode * HID + kb * 32 + quad * 8];
    }
    float sa[4];
#pragma unroll
    for (int e = 0; e < 4; e++) sa[e] = sumatt[node0 + wave * 16 + quad * 4 + e];

    floatx4 acc_i[8], acc_h[8], gr_[8], gn_[8];

    // ================= gate r (g=0) =================
#pragma unroll
    for (int tc = 0; tc < 8; tc++) {
        int f = 0 * 128 + tc * 16 + col;
        float bi = bih[f], bm = bmih[f], bh = bhh[f];
        acc_i[tc] = (floatx4){bi + sa[0] * bm, bi + sa[1] * bm, bi + sa[2] * bm, bi + sa[3] * bm};
        acc_h[tc] = (floatx4){bh, bh, bh, bh};
    }
    LOADW(wcb + 0 * 16384); MM(afA, acc_i);
    LOADW(whhb + 0 * 16384); MM(afX, acc_h);
#pragma unroll
    for (int tc = 0; tc < 8; tc++)
#pragma unroll
        for (int e = 0; e < 4; e++)
            gr_[tc][e] = sigm(acc_i[tc][e] + acc_h[tc][e]);

    // ================= gate n (g=2) =================
#pragma unroll
    for (int tc = 0; tc < 8; tc++) {
        int f = 2 * 128 + tc * 16 + col;
        float bi = bih[f], bm = bmih[f], bh = bhh[f];
        acc_i[tc] = (floatx4){bi + sa[0] * bm, bi + sa[1] * bm, bi + sa[2] * bm, bi + sa[3] * bm};
        acc_h[tc] = (floatx4){bh, bh, bh, bh};
    }
    LOADW(wcb + 2 * 16384); MM(afA, acc_i);
    LOADW(whhb + 2 * 16384); MM(afX, acc_h);
#pragma unroll
    for (int tc = 0; tc < 8; tc++)
#pragma unroll
        for (int e = 0; e < 4; e++)
            gn_[tc][e] = tanhf(acc_i[tc][e] + gr_[tc][e] * acc_h[tc][e]);

    // ================= gate z (g=1) + h =================
#pragma unroll
    for (int tc = 0; tc < 8; tc++) {
        int f = 1 * 128 + tc * 16 + col;
        float bi = bih[f], bm = bmih[f], bh = bhh[f];
        acc_i[tc] = (floatx4){bi + sa[0] * bm, bi + sa[1] * bm, bi + sa[2] * bm, bi + sa[3] * bm};
        acc_h[tc] = (floatx4){bh, bh, bh, bh};
    }
    LOADW(wcb + 1 * 16384); MM(afA, acc_i);
    LOADW(whhb + 1 * 16384); MM(afX, acc_h);

    __syncthreads();                          // done reading sW as weights
    float* hst = (float*)sW;                  // 64 x 128 fp32 = 32 KB
#pragma unroll
    for (int tc = 0; tc < 8; tc++) {
#pragma unroll
        for (int e = 0; e < 4; e++) {
            float z = sigm(acc_i[tc][e] + acc_h[tc][e]);
            int nd = node0 + wave * 16 + quad * 4 + e;
            float xv = x[(size_t)nd * HID + tc * 16 + col];
            float h = (1.0f - z) * gn_[tc][e] + z * xv;
            hst[(wave * 16 + quad * 4 + e) * 128 + tc * 16 + col] = h;
        }
    }
    __syncthreads();

    // coalesced y write
#pragma unroll
    for (int i = 0; i < 32; i++) {
        int idx = t + i * 256;
        if (node0 + (idx >> 7) < NN) y[(size_t)node0 * HID + idx] = hst[idx];
    }
    // BN partial sums
    if (t < 128) {
        int count = NN - node0; if (count > 64) count = 64;
        float s = 0.f, s2 = 0.f;
        for (int m = 0; m < count; m++) { float v = hst[m * 128 + t]; s += v; s2 += v * v; }
        unsafeAtomicAdd(&bnsum[t], (double)s);
        unsafeAtomicAdd(&bnsum[128 + t], (double)s2);
    }
}

// ---------------------------------------------------------------------------
// Segmented sum-pool (batch_idx is SORTED): block = 256 threads covering a
// 256-node chunk; thread t owns feature f=t&127 of stream s=t>>7 (even/odd
// nodes interleaved). Register-accumulate, flush one atomic per graph
// boundary (~1-2 per chunk). grid 196.
// ---------------------------------------------------------------------------
__global__ __launch_bounds__(256) void k_pool(
    const float* __restrict__ x, const int* __restrict__ batch, float* __restrict__ gr)
{
    __shared__ int sb[256];
    const int t = threadIdx.x;
    const int nb = blockIdx.x * 256;
    int ld = nb + t; if (ld >= NN) ld = NN - 1;
    sb[t] = batch[ld];
    __syncthreads();
    const int s = t >> 7, f = t & 127;
    float acc = 0.f; int cur = -1;
    for (int i = s; i < 256; i += 2) {
        int n = nb + i;
        if (n >= NN) break;
        int g = sb[i];
        if (g != cur) {
            if (cur >= 0) unsafeAtomicAdd(&gr[(size_t)cur * HID + f], acc);
            acc = 0.f; cur = g;
        }
        acc += x[(size_t)n * HID + f];
    }
    if (cur >= 0) unsafeAtomicAdd(&gr[(size_t)cur * HID + f], acc);
}

// ---------------------------------------------------------------------------
// Readout: out[g] = relu(gr[g] @ W1^T + b1) @ W2^T + b2   (128 blocks x 64)
// ---------------------------------------------------------------------------
__global__ __launch_bounds__(64) void k_readout(
    const float* __restrict__ gr, const float* __restrict__ W1,
    const float* __restrict__ b1, const float* __restrict__ W2,
    const float* __restrict__ b2, float* __restrict__ out)
{
    const int g = blockIdx.x, j = threadIdx.x;
    float acc = b1[j];
    const float4* grow = (const float4*)&gr[g * HID];
    const float4* wrow = (const float4*)&W1[j * HID];
#pragma unroll
    for (int k4 = 0; k4 < 32; k4++) {
        float4 a = grow[k4], w = wrow[k4];
        acc += a.x * w.x + a.y * w.y + a.z * w.z + a.w * w.w;
    }
    float h = fmaxf(acc, 0.0f) * W2[j];
#pragma unroll
    for (int msk = 32; msk >= 1; msk >>= 1) h += __shfl_xor(h, msk);
    if (j == 0) out[g] = h + b2[0];
}

// ---------------------------------------------------------------------------
extern "C" void kernel_launch(void* const* d_in, const int* in_sizes, int n_in,
                              void* d_out, int out_size, void* d_ws, size_t ws_size,
                              hipStream_t stream)
{
    const float* nf    = (const float*)d_in[0];
    const int*   ei    = (const int*)d_in[1];
    const int*   batch = (const int*)d_in[2];
    const float* embW  = (const float*)d_in[3];
    const float* embb  = (const float*)d_in[4];
    const float* embg  = (const float*)d_in[5];
    const float* embbe = (const float*)d_in[6];
    const float* msgW  = (const float*)d_in[7];
    const float* msgb  = (const float*)d_in[8];
    const float* attW  = (const float*)d_in[9];
    const float* attb  = (const float*)d_in[10];
    const float* Wih   = (const float*)d_in[11];
    const float* bih   = (const float*)d_in[12];
    const float* Whh   = (const float*)d_in[13];
    const float* bhh   = (const float*)d_in[14];
    const float* bng   = (const float*)d_in[15];
    const float* bnb   = (const float*)d_in[16];
    const float* roW1  = (const float*)d_in[17];
    const float* rob1  = (const float*)d_in[18];
    const float* roW2  = (const float*)d_in[19];
    const float* rob2  = (const float*)d_in[20];
    const int* src = ei;
    const int* dst = ei + NE;
    float* out = (float*)d_out;

    // ---- workspace layout (all sections 16B-multiple) ----
    char* base = (char*)d_ws;
    const size_t NH = (size_t)NN * HID;      // 6.4M elements
    double* bnsum = (double*)base;           // 256 doubles = 2048 B
    float* x     = (float*)(base + 2048);    // fp32 node state
    float* y     = x + NH;                   // pre-BN state
    unsigned short* xb    = (unsigned short*)(y + NH);   // bf16 mirror of x
    unsigned short* aggxb = xb + NH;                     // bf16 gather output
    float* as_   = (float*)(aggxb + NH);
    float* ad_   = as_ + NN;
    float* sumatt= ad_ + NN;
    float* ss    = sumatt + NN;              // 256: scale|shift
    float* gr    = ss + 256;                 // 128*128
    float* Wc    = gr + NGRAPHS * HID;       // 4*384*128 fp32
    float* bmih  = Wc + 4 * 384 * 128;       // 4*384
    int* rowptr  = (int*)(bmih + 4 * 384);   // NN+4 (padded for alignment)
    int* wptr    = rowptr + NN + 4;          // NN
    int* cnt     = wptr + NN;                // NN
    int* bsum    = cnt + NN;                 // 128 (scan block totals)
    int* ssrc    = bsum + 128;               // NE
    unsigned short* wcb  = (unsigned short*)(ssrc + NE); // 4*49152 bf16 frags
    unsigned short* whhb = wcb + 4 * 49152;              // 4*49152 bf16 frags

    // ---- once-per-call precompute: combined weights (+bf16 frags) + CSR ----
    k_wc<<<4 * 384, 128, 0, stream>>>(Wih, msgW, msgb, Wc, bmih);
    k_frag<<<8 * 192, 256, 0, stream>>>(Wc, Whh, wcb, whhb);
    hipMemsetAsync(cnt, 0, NN * sizeof(int), stream);
    k_count<<<(NE + 255) / 256, 256, 0, stream>>>(dst, cnt);
    k_scan1<<<SCAN_G, SCAN_B, 0, stream>>>(cnt, rowptr, bsum);
    k_scan2<<<1, 128, 0, stream>>>(bsum, rowptr);
    k_scan3<<<SCAN_G, SCAN_B, 0, stream>>>(rowptr, bsum, wptr);
    k_scatter<<<(NE + 255) / 256, 256, 0, stream>>>(src, dst, wptr, ssrc);

    // ---- embedding + BN + att-proj for layer 0 ----
    hipMemsetAsync(bnsum, 0, 256 * sizeof(double), stream);
    k_embed<<<NN / TN, 256, 0, stream>>>(nf, embW, embb, y, bnsum);
    k_bnfin<<<1, 128, 0, stream>>>(bnsum, embg, embbe, ss);
    k_bnx<<<NN / 4, 256, 0, stream>>>(y, ss, attW, x, xb, as_, ad_);

    for (int l = 0; l < NLAYERS; l++) {
        k_gather<<<NN / 8, 256, 0, stream>>>(rowptr, ssrc, xb, as_, ad_, attb, l, aggxb, sumatt);
        hipMemsetAsync(bnsum, 0, 256 * sizeof(double), stream);
        k_gru<<<(NN + 63) / 64, 256, 0, stream>>>(
            aggxb, sumatt, xb, x,
            wcb + (size_t)l * 49152, bmih + (size_t)l * 384, bih + (size_t)l * 384,
            whhb + (size_t)l * 49152, bhh + (size_t)l * 384, y, bnsum);
        k_bnfin<<<1, 128, 0, stream>>>(bnsum, bng + (size_t)l * HID, bnb + (size_t)l * HID, ss);
        const float* attW_next = attW + (size_t)((l + 1 < NLAYERS) ? l + 1 : l) * 256;
        k_bnx<<<NN / 4, 256, 0, stream>>>(y, ss, attW_next, x, xb, as_, ad_);
    }

    hipMemsetAsync(gr, 0, NGRAPHS * HID * sizeof(float), stream);
    k_pool<<<(NN + 255) / 256, 256, 0, stream>>>(x, batch, gr);
    k_readout<<<NGRAPHS, 64, 0, stream>>>(gr, roW1, rob1, roW2, rob2, out);
}

// Round 6
// 772.736 us; speedup vs baseline: 7.6884x; 1.0660x over previous
//
#include <hip/hip_runtime.h>
#include <math.h>

#define NN 50000
#define NE 600000
#define ADIM 75
#define HID 128
#define NLAYERS 4
#define NGRAPHS 128
#define BN_EPS 1e-5f
#define NNP 50048   // NN padded to 64-node blocks

typedef short bhalf8 __attribute__((ext_vector_type(8)));
typedef float floatx4 __attribute__((ext_vector_type(4)));

__device__ __forceinline__ float sigm(float v) { return 1.0f / (1.0f + __expf(-v)); }

// fp32 -> bf16 with round-to-nearest-even
__device__ __forceinline__ unsigned short f2bf(float f) {
    unsigned u = __builtin_bit_cast(unsigned, f);
    u = (u + 0x7FFFu + ((u >> 16) & 1u)) >> 16;
    return (unsigned short)u;
}
__device__ __forceinline__ float bf2f(unsigned short h) {
    return __builtin_bit_cast(float, ((unsigned)h) << 16);
}

// ---------------------------------------------------------------------------
// nf [NN x 75] fp32 -> nfb [NNP x 96] bf16 (K zero-padded 75->96)
// thread owns 4 consecutive k of one node; grid 4688 x 256
// ---------------------------------------------------------------------------
__global__ __launch_bounds__(256) void k_nfb(
    const float* __restrict__ nf, unsigned short* __restrict__ nfb)
{
    int e = blockIdx.x * 256 + threadIdx.x;      // (n, k4): 50000*24
    if (e >= NN * 24) return;
    int n = e / 24, k4 = e - n * 24;
    ushort4 o;
    int k = k4 * 4;
    o.x = (k + 0 < ADIM) ? f2bf(nf[(size_t)n * ADIM + k + 0]) : 0;
    o.y = (k + 1 < ADIM) ? f2bf(nf[(size_t)n * ADIM + k + 1]) : 0;
    o.z = (k + 2 < ADIM) ? f2bf(nf[(size_t)n * ADIM + k + 2]) : 0;
    o.w = (k + 3 < ADIM) ? f2bf(nf[(size_t)n * ADIM + k + 3]) : 0;
    ((ushort4*)nfb)[(size_t)n * 24 + k4] = o;
}

// ---------------------------------------------------------------------------
// embW [128 x 75] -> bf16 B-fragments, K padded to 96:
//   layout [tc(8)][kb(3)][quad(4)][n(16)][j(8)], elem = W[tc*16+n][kb*32+quad*8+j]
// grid 48 x 256 (12288 elements)
// ---------------------------------------------------------------------------
__global__ __launch_bounds__(256) void k_wfrag_emb(
    const float* __restrict__ W, unsigned short* __restrict__ web)
{
    int e = blockIdx.x * 256 + threadIdx.x;      // 0..12287
    int j = e & 7, n = (e >> 3) & 15, quad = (e >> 7) & 3;
    int kb = (e >> 9) % 3, tc = e / 1536;
    int row = tc * 16 + n;
    int kk = kb * 32 + quad * 8 + j;
    web[e] = (kk < ADIM) ? f2bf(W[row * ADIM + kk]) : 0;
}

// ---------------------------------------------------------------------------
// MFMA embedding: y = relu(nf @ embW^T + b), BN sums.
// block 256 = 4 waves x 16 nodes (64 nodes/block); grid 782.
// Weights (24 KB frag-ordered) streamed via global_load_lds once.
// ---------------------------------------------------------------------------
__global__ __launch_bounds__(256) void k_embed_m(
    const unsigned short* __restrict__ nfb, const unsigned short* __restrict__ web,
    const float* __restrict__ b, float* __restrict__ y,
    double* __restrict__ bnsum)
{
    __shared__ __align__(16) short sWe[16384];   // 32 KB: 24 KB weights, reused as h-stage
    const int t = threadIdx.x;
    const int wave = t >> 6, lane = t & 63;
    const int col = lane & 15, quad = (lane >> 4) & 3;
    const int node0 = blockIdx.x * 64;

    // stage weight frags: 12288 shorts = 6 x 256 lanes x 8 shorts
#pragma unroll
    for (int i = 0; i < 6; i++) {
        int idx = i * 256 + wave * 64 + lane;
        const unsigned short* gp = web + idx * 8;
        short* lp = sWe + idx * 8;
        __builtin_amdgcn_global_load_lds(
            (__attribute__((address_space(1))) void*)gp,
            (__attribute__((address_space(3))) void*)lp, 16, 0, 0);
    }

    // A-fragments: nfb rows, A[m=col][k=quad*8+j], 3 K-blocks
    const int anode = node0 + wave * 16 + col;
    bhalf8 afN[3];
#pragma unroll
    for (int kb = 0; kb < 3; kb++)
        afN[kb] = *(const bhalf8*)&nfb[(size_t)anode * 96 + kb * 32 + quad * 8];

    floatx4 acc[8];
#pragma unroll
    for (int tc = 0; tc < 8; tc++) {
        float bv = b[tc * 16 + col];
        acc[tc] = (floatx4){bv, bv, bv, bv};
    }
    __syncthreads();

#pragma unroll
    for (int tc = 0; tc < 8; tc++)
#pragma unroll
        for (int kb = 0; kb < 3; kb++) {
            bhalf8 bf = *(const bhalf8*)&sWe[(((tc * 3 + kb) * 4 + quad) * 16 + col) * 8];
            acc[tc] = __builtin_amdgcn_mfma_f32_16x16x32_bf16(afN[kb], bf, acc[tc], 0, 0, 0);
        }

    __syncthreads();                          // done reading weights
    float* hst = (float*)sWe;                 // 64 x 128 fp32
#pragma unroll
    for (int tc = 0; tc < 8; tc++)
#pragma unroll
        for (int e = 0; e < 4; e++) {
            float v = fmaxf(acc[tc][e], 0.0f);
            hst[(wave * 16 + quad * 4 + e) * 128 + tc * 16 + col] = v;
        }
    __syncthreads();

#pragma unroll
    for (int i = 0; i < 32; i++) {
        int idx = t + i * 256;
        if (node0 + (idx >> 7) < NN) y[(size_t)node0 * HID + idx] = hst[idx];
    }
    if (t < 128) {
        int count = NN - node0; if (count > 64) count = 64;
        float s = 0.f, s2 = 0.f;
        for (int m = 0; m < count; m++) { float v = hst[m * 128 + t]; s += v; s2 += v * v; }
        unsafeAtomicAdd(&bnsum[t], (double)s);
        unsafeAtomicAdd(&bnsum[128 + t], (double)s2);
    }
}

// ---------------------------------------------------------------------------
// BN finalize: scale/shift from double sums
// ---------------------------------------------------------------------------
__global__ void k_bnfin(const double* __restrict__ bnsum, const float* __restrict__ g,
                        const float* __restrict__ beta, float* __restrict__ ss)
{
    int f = threadIdx.x;
    double mean = bnsum[f] / (double)NN;
    double var  = bnsum[128 + f] / (double)NN - mean * mean;
    float inv = rsqrtf((float)var + BN_EPS);
    float sc = g[f] * inv;
    ss[f] = sc;
    ss[128 + f] = beta[f] - (float)mean * sc;
}

// ---------------------------------------------------------------------------
// Fused BN-apply + bf16 mirror + attention projections for the NEXT layer:
//   x = y*scale + shift ; xb = bf16(x) ; as_[n] = x.attW[:128] ; ad_ = x.attW[128:]
// block 256 = 4 nodes x 64 lanes (float2/lane); grid 12500
// ---------------------------------------------------------------------------
__global__ __launch_bounds__(256) void k_bnx(
    const float* __restrict__ y, const float* __restrict__ ss,
    const float* __restrict__ attW, float* __restrict__ x,
    unsigned short* __restrict__ xb,
    float* __restrict__ as_, float* __restrict__ ad_)
{
    const int t = threadIdx.x;
    const int n = blockIdx.x * 4 + (t >> 6);
    const int lane = t & 63;
    float2 sc = ((const float2*)ss)[lane];
    float2 sh = ((const float2*)(ss + 128))[lane];
    float2 v = ((const float2*)y)[(size_t)n * 64 + lane];
    float2 xv;
    xv.x = v.x * sc.x + sh.x;
    xv.y = v.y * sc.y + sh.y;
    ((float2*)x)[(size_t)n * 64 + lane] = xv;
    unsigned pk = (unsigned)f2bf(xv.x) | ((unsigned)f2bf(xv.y) << 16);
    ((unsigned*)xb)[(size_t)n * 64 + lane] = pk;
    float2 aws = ((const float2*)attW)[lane];
    float2 awd = ((const float2*)(attW + 128))[lane];
    float pas = xv.x * aws.x + xv.y * aws.y;
    float pad = xv.x * awd.x + xv.y * awd.y;
#pragma unroll
    for (int msk = 32; msk >= 1; msk >>= 1) {
        pas += __shfl_xor(pas, msk);
        pad += __shfl_xor(pad, msk);
    }
    if (lane == 0) { as_[n] = pas; ad_[n] = pad; }
}

// ---------------------------------------------------------------------------
// Combined-weight precompute: Wc[l] = Wih[l] @ Wm[l]  [384x128],
//                             bmih[l] = Wih[l] @ bm[l] [384]
// grid 4*384 blocks x 128 threads
// ---------------------------------------------------------------------------
__global__ __launch_bounds__(128) void k_wc(
    const float* __restrict__ Wih, const float* __restrict__ Wm,
    const float* __restrict__ bm, float* __restrict__ Wc, float* __restrict__ bmih)
{
    __shared__ float sw[128];
    __shared__ float red[128];
    const int b = blockIdx.x;
    const int l = b / 384, r = b - l * 384;
    const int t = threadIdx.x;
    const float* wihrow = Wih + ((size_t)l * 384 + r) * 128;
    sw[t] = wihrow[t];
    __syncthreads();
    const float* wm = Wm + (size_t)l * 128 * 128;
    float acc = 0.f;
#pragma unroll 8
    for (int k = 0; k < 128; k++) acc += sw[k] * wm[k * 128 + t];
    Wc[((size_t)l * 384 + r) * 128 + t] = acc;
    red[t] = sw[t] * bm[l * 128 + t];
    __syncthreads();
#pragma unroll
    for (int off = 64; off >= 1; off >>= 1) {
        if (t < off) red[t] += red[t + off];
        __syncthreads();
    }
    if (t == 0) bmih[l * 384 + r] = red[0];
}

// ---------------------------------------------------------------------------
// Convert Wc (fp32, [L][384][128]) and Whh to bf16 in MFMA B-fragment order:
//   layout [gate(3)][tc(8)][kb(4)][quad(4)][n(16)][j(8)] per layer-matrix
//   element = W[gate*128 + tc*16 + n][kb*32 + quad*8 + j]
// grid 8 mats * 192 blocks x 256 threads
// ---------------------------------------------------------------------------
__global__ __launch_bounds__(256) void k_frag(
    const float* __restrict__ Wc, const float* __restrict__ Whh,
    unsigned short* __restrict__ wcb, unsigned short* __restrict__ whhb)
{
    const int b = blockIdx.x;
    const int mat = b / 192;
    const int e = (b - mat * 192) * 256 + threadIdx.x;   // 0..49151
    const int l = mat >> 1, which = mat & 1;
    const float* src = which ? (Whh + (size_t)l * 49152) : (Wc + (size_t)l * 49152);
    unsigned short* dst = which ? (whhb + (size_t)l * 49152) : (wcb + (size_t)l * 49152);
    int j = e & 7, n = (e >> 3) & 15, quad = (e >> 7) & 3;
    int kb = (e >> 9) & 3, tc = (e >> 11) & 7, g = (e >> 14) & 3;
    int row = g * 128 + tc * 16 + n;
    int kk = kb * 32 + quad * 8 + j;
    dst[e] = f2bf(src[row * 128 + kk]);
}

// ---------------------------------------------------------------------------
// CSR build: histogram, 3-kernel device-wide scan, scatter
// ---------------------------------------------------------------------------
__global__ __launch_bounds__(256) void k_count(const int* __restrict__ dst, int* __restrict__ cnt)
{
    int e = blockIdx.x * 256 + threadIdx.x;
    if (e < NE) atomicAdd(&cnt[dst[e]], 1);
}

#define SCAN_B 512
#define SCAN_G 98          // 98*512 = 50176 >= 50000

// stage 1: intra-block exclusive scan of cnt -> rowptr (local), block totals
__global__ __launch_bounds__(SCAN_B) void k_scan1(
    const int* __restrict__ cnt, int* __restrict__ rowptr, int* __restrict__ bsum)
{
    __shared__ int s[SCAN_B];
    const int t = threadIdx.x;
    const int i = blockIdx.x * SCAN_B + t;
    int v = (i < NN) ? cnt[i] : 0;
    s[t] = v;
    __syncthreads();
#pragma unroll
    for (int off = 1; off < SCAN_B; off <<= 1) {
        int u = (t >= off) ? s[t - off] : 0;
        __syncthreads();
        s[t] += u;
        __syncthreads();
    }
    if (i < NN) rowptr[i] = s[t] - v;        // local exclusive
    if (t == SCAN_B - 1) bsum[blockIdx.x] = s[t];
}

// stage 2: exclusive scan of the 98 block totals (one small block)
__global__ __launch_bounds__(128) void k_scan2(int* __restrict__ bsum, int* __restrict__ rowptr)
{
    __shared__ int s[128];
    const int t = threadIdx.x;
    int v = (t < SCAN_G) ? bsum[t] : 0;
    s[t] = v;
    __syncthreads();
#pragma unroll
    for (int off = 1; off < 128; off <<= 1) {
        int u = (t >= off) ? s[t - off] : 0;
        __syncthreads();
        s[t] += u;
        __syncthreads();
    }
    if (t < SCAN_G) bsum[t] = s[t] - v;      // exclusive offsets
    if (t == 127) rowptr[NN] = s[127];       // grand total (= NE)
}

// stage 3: add block offsets; emit wptr copy
__global__ __launch_bounds__(SCAN_B) void k_scan3(
    int* __restrict__ rowptr, const int* __restrict__ bsum, int* __restrict__ wptr)
{
    const int i = blockIdx.x * SCAN_B + threadIdx.x;
    if (i < NN) {
        int v = rowptr[i] + bsum[blockIdx.x];
        rowptr[i] = v;
        wptr[i] = v;
    }
}

__global__ __launch_bounds__(256) void k_scatter(
    const int* __restrict__ src, const int* __restrict__ dst,
    int* __restrict__ wptr, int* __restrict__ ssrc)
{
    int e = blockIdx.x * 256 + threadIdx.x;
    if (e < NE) {
        int d = dst[e];
        int pos = atomicAdd(&wptr[d], 1);
        ssrc[pos] = src[e];
    }
}

// ---------------------------------------------------------------------------
// Gather-aggregate over bf16 x-table (no atomics), software-pipelined:
//   aggxb[d] = bf16( sum_e att_e * xb[src_e] ) ; sumatt[d] = sum_e att_e
// att_e = sigmoid(as_[s] + ad_[d] + attb[l])
// block 256 = 8 nodes x 32 lanes (ushort4 = 4 feats/lane); grid 6250
// ---------------------------------------------------------------------------
__global__ __launch_bounds__(256) void k_gather(
    const int* __restrict__ rowptr, const int* __restrict__ ssrc,
    const unsigned short* __restrict__ xb, const float* __restrict__ as_,
    const float* __restrict__ ad_, const float* __restrict__ attb, int l,
    unsigned short* __restrict__ aggxb, float* __restrict__ sumatt)
{
    const int t = threadIdx.x;
    const int n = blockIdx.x * 8 + (t >> 5);
    const int lane = t & 31;
    const int r0 = rowptr[n], r1 = rowptr[n + 1];
    const float adv = ad_[n] + attb[l];
    float4 acc = make_float4(0.f, 0.f, 0.f, 0.f);
    float satt = 0.f;
    if (r0 < r1) {
        int s = ssrc[r0];
        ushort4 v = ((const ushort4*)xb)[(size_t)s * 32 + lane];
        float a = as_[s];
        for (int i = r0; i < r1; i++) {
            // prefetch edge i+1 while computing edge i
            int s2 = (i + 1 < r1) ? ssrc[i + 1] : s;
            ushort4 v2 = ((const ushort4*)xb)[(size_t)s2 * 32 + lane];
            float a2 = as_[s2];
            float att = sigm(a + adv);
            acc.x += bf2f(v.x) * att; acc.y += bf2f(v.y) * att;
            acc.z += bf2f(v.z) * att; acc.w += bf2f(v.w) * att;
            satt += att;
            v = v2; a = a2;
        }
    }
    ushort4 o;
    o.x = f2bf(acc.x); o.y = f2bf(acc.y); o.z = f2bf(acc.z); o.w = f2bf(acc.w);
    ((ushort4*)aggxb)[(size_t)n * 32 + lane] = o;
    if (lane == 0) sumatt[n] = satt;
}

// ---------------------------------------------------------------------------
// MFMA GRU: gi = aggx@Wc^T + sumatt*bmih + bih ; gh = x@Whh^T + bhh
//           gates, h_new, BN sums.
// block 256 = 4 waves x 16 nodes each (64 nodes/block); grid 782.
// ---------------------------------------------------------------------------
#define LOADW(PTR)                                                            \
    __syncthreads();                                                          \
    _Pragma("unroll")                                                         \
    for (int i = 0; i < 8; i++) {                                             \
        const unsigned short* gp = (PTR) + ((wave * 8 + i) * 64 + lane) * 8;  \
        short* lp = sW + (wave * 8 + i) * 512;                                \
        __builtin_amdgcn_global_load_lds(                                     \
            (__attribute__((address_space(1))) void*)gp,                      \
            (__attribute__((address_space(3))) void*)lp, 16, 0, 0);           \
    }                                                                         \
    __syncthreads();

#define MM(AF, ACC)                                                           \
    _Pragma("unroll")                                                         \
    for (int tc = 0; tc < 8; tc++) {                                          \
        _Pragma("unroll")                                                     \
        for (int kb = 0; kb < 4; kb++) {                                      \
            bhalf8 bf = *(const bhalf8*)&sW[(((tc * 4 + kb) * 4 + quad) * 16 + col) * 8]; \
            ACC[tc] = __builtin_amdgcn_mfma_f32_16x16x32_bf16(AF[kb], bf, ACC[tc], 0, 0, 0); \
        }                                                                     \
    }

__global__ __launch_bounds__(256) void k_gru(
    const unsigned short* __restrict__ aggxb, const float* __restrict__ sumatt,
    const unsigned short* __restrict__ xb, const float* __restrict__ x,
    const unsigned short* __restrict__ wcb, const float* __restrict__ bmih,
    const float* __restrict__ bih,
    const unsigned short* __restrict__ whhb, const float* __restrict__ bhh,
    float* __restrict__ y, double* __restrict__ bnsum)
{
    __shared__ __align__(16) short sW[128 * 128];   // 32 KB; reused as h-stage fp32
    const int t = threadIdx.x;
    const int wave = t >> 6, lane = t & 63;
    const int col = lane & 15, quad = (lane >> 4) & 3;
    const int node0 = blockIdx.x * 64;

    // ---- A-fragments: direct bf16 16B loads, A[m=lane&15][k=quad*8+j] ----
    const int anode = node0 + wave * 16 + col;
    bhalf8 afA[4], afX[4];
#pragma unroll
    for (int kb = 0; kb < 4; kb++) {
        afA[kb] = *(const bhalf8*)&aggxb[(size_t)anode * HID + kb * 32 + quad * 8];
        afX[kb] = *(const bhalf8*)&xb[(size_t)anode * HID + kb * 32 + quad * 8];
    }
    float sa[4];
#pragma unroll
    for (int e = 0; e < 4; e++) sa[e] = sumatt[node0 + wave * 16 + quad * 4 + e];

    floatx4 acc_i[8], acc_h[8], gr_[8], gn_[8];

    // ================= gate r (g=0) =================
#pragma unroll
    for (int tc = 0; tc < 8; tc++) {
        int f = 0 * 128 + tc * 16 + col;
        float bi = bih[f], bm = bmih[f], bh = bhh[f];
        acc_i[tc] = (floatx4){bi + sa[0] * bm, bi + sa[1] * bm, bi + sa[2] * bm, bi + sa[3] * bm};
        acc_h[tc] = (floatx4){bh, bh, bh, bh};
    }
    LOADW(wcb + 0 * 16384); MM(afA, acc_i);
    LOADW(whhb + 0 * 16384); MM(afX, acc_h);
#pragma unroll
    for (int tc = 0; tc < 8; tc++)
#pragma unroll
        for (int e = 0; e < 4; e++)
            gr_[tc][e] = sigm(acc_i[tc][e] + acc_h[tc][e]);

    // ================= gate n (g=2) =================
#pragma unroll
    for (int tc = 0; tc < 8; tc++) {
        int f = 2 * 128 + tc * 16 + col;
        float bi = bih[f], bm = bmih[f], bh = bhh[f];
        acc_i[tc] = (floatx4){bi + sa[0] * bm, bi + sa[1] * bm, bi + sa[2] * bm, bi + sa[3] * bm};
        acc_h[tc] = (floatx4){bh, bh, bh, bh};
    }
    LOADW(wcb + 2 * 16384); MM(afA, acc_i);
    LOADW(whhb + 2 * 16384); MM(afX, acc_h);
#pragma unroll
    for (int tc = 0; tc < 8; tc++)
#pragma unroll
        for (int e = 0; e < 4; e++)
            gn_[tc][e] = tanhf(acc_i[tc][e] + gr_[tc][e] * acc_h[tc][e]);

    // ================= gate z (g=1) + h =================
#pragma unroll
    for (int tc = 0; tc < 8; tc++) {
        int f = 1 * 128 + tc * 16 + col;
        float bi = bih[f], bm = bmih[f], bh = bhh[f];
        acc_i[tc] = (floatx4){bi + sa[0] * bm, bi + sa[1] * bm, bi + sa[2] * bm, bi + sa[3] * bm};
        acc_h[tc] = (floatx4){bh, bh, bh, bh};
    }
    LOADW(wcb + 1 * 16384); MM(afA, acc_i);
    LOADW(whhb + 1 * 16384); MM(afX, acc_h);

    __syncthreads();                          // done reading sW as weights
    float* hst = (float*)sW;                  // 64 x 128 fp32 = 32 KB
#pragma unroll
    for (int tc = 0; tc < 8; tc++) {
#pragma unroll
        for (int e = 0; e < 4; e++) {
            float z = sigm(acc_i[tc][e] + acc_h[tc][e]);
            int nd = node0 + wave * 16 + quad * 4 + e;
            float xv = x[(size_t)nd * HID + tc * 16 + col];
            float h = (1.0f - z) * gn_[tc][e] + z * xv;
            hst[(wave * 16 + quad * 4 + e) * 128 + tc * 16 + col] = h;
        }
    }
    __syncthreads();

    // coalesced y write
#pragma unroll
    for (int i = 0; i < 32; i++) {
        int idx = t + i * 256;
        if (node0 + (idx >> 7) < NN) y[(size_t)node0 * HID + idx] = hst[idx];
    }
    // BN partial sums
    if (t < 128) {
        int count = NN - node0; if (count > 64) count = 64;
        float s = 0.f, s2 = 0.f;
        for (int m = 0; m < count; m++) { float v = hst[m * 128 + t]; s += v; s2 += v * v; }
        unsafeAtomicAdd(&bnsum[t], (double)s);
        unsafeAtomicAdd(&bnsum[128 + t], (double)s2);
    }
}

// ---------------------------------------------------------------------------
// Segmented sum-pool (batch_idx is SORTED)
// ---------------------------------------------------------------------------
__global__ __launch_bounds__(256) void k_pool(
    const float* __restrict__ x, const int* __restrict__ batch, float* __restrict__ gr)
{
    __shared__ int sb[256];
    const int t = threadIdx.x;
    const int nb = blockIdx.x * 256;
    int ld = nb + t; if (ld >= NN) ld = NN - 1;
    sb[t] = batch[ld];
    __syncthreads();
    const int s = t >> 7, f = t & 127;
    float acc = 0.f; int cur = -1;
    for (int i = s; i < 256; i += 2) {
        int n = nb + i;
        if (n >= NN) break;
        int g = sb[i];
        if (g != cur) {
            if (cur >= 0) unsafeAtomicAdd(&gr[(size_t)cur * HID + f], acc);
            acc = 0.f; cur = g;
        }
        acc += x[(size_t)n * HID + f];
    }
    if (cur >= 0) unsafeAtomicAdd(&gr[(size_t)cur * HID + f], acc);
}

// ---------------------------------------------------------------------------
// Readout: out[g] = relu(gr[g] @ W1^T + b1) @ W2^T + b2   (128 blocks x 64)
// ---------------------------------------------------------------------------
__global__ __launch_bounds__(64) void k_readout(
    const float* __restrict__ gr, const float* __restrict__ W1,
    const float* __restrict__ b1, const float* __restrict__ W2,
    const float* __restrict__ b2, float* __restrict__ out)
{
    const int g = blockIdx.x, j = threadIdx.x;
    float acc = b1[j];
    const float4* grow = (const float4*)&gr[g * HID];
    const float4* wrow = (const float4*)&W1[j * HID];
#pragma unroll
    for (int k4 = 0; k4 < 32; k4++) {
        float4 a = grow[k4], w = wrow[k4];
        acc += a.x * w.x + a.y * w.y + a.z * w.z + a.w * w.w;
    }
    float h = fmaxf(acc, 0.0f) * W2[j];
#pragma unroll
    for (int msk = 32; msk >= 1; msk >>= 1) h += __shfl_xor(h, msk);
    if (j == 0) out[g] = h + b2[0];
}

// ---------------------------------------------------------------------------
extern "C" void kernel_launch(void* const* d_in, const int* in_sizes, int n_in,
                              void* d_out, int out_size, void* d_ws, size_t ws_size,
                              hipStream_t stream)
{
    const float* nf    = (const float*)d_in[0];
    const int*   ei    = (const int*)d_in[1];
    const int*   batch = (const int*)d_in[2];
    const float* embW  = (const float*)d_in[3];
    const float* embb  = (const float*)d_in[4];
    const float* embg  = (const float*)d_in[5];
    const float* embbe = (const float*)d_in[6];
    const float* msgW  = (const float*)d_in[7];
    const float* msgb  = (const float*)d_in[8];
    const float* attW  = (const float*)d_in[9];
    const float* attb  = (const float*)d_in[10];
    const float* Wih   = (const float*)d_in[11];
    const float* bih   = (const float*)d_in[12];
    const float* Whh   = (const float*)d_in[13];
    const float* bhh   = (const float*)d_in[14];
    const float* bng   = (const float*)d_in[15];
    const float* bnb   = (const float*)d_in[16];
    const float* roW1  = (const float*)d_in[17];
    const float* rob1  = (const float*)d_in[18];
    const float* roW2  = (const float*)d_in[19];
    const float* rob2  = (const float*)d_in[20];
    const int* src = ei;
    const int* dst = ei + NE;
    float* out = (float*)d_out;

    // ---- workspace layout (all sections 16B-multiple) ----
    char* base = (char*)d_ws;
    const size_t NH = (size_t)NN * HID;      // 6.4M elements
    double* bnsum = (double*)base;           // 256 doubles = 2048 B
    float* x     = (float*)(base + 2048);    // fp32 node state
    float* y     = x + NH;                   // pre-BN state
    unsigned short* xb    = (unsigned short*)(y + NH);   // bf16 mirror of x
    unsigned short* aggxb = xb + NH;                     // bf16 gather output
    float* as_   = (float*)(aggxb + NH);
    float* ad_   = as_ + NN;
    float* sumatt= ad_ + NN;
    float* ss    = sumatt + NN;              // 256: scale|shift
    float* gr    = ss + 256;                 // 128*128
    float* Wc    = gr + NGRAPHS * HID;       // 4*384*128 fp32
    float* bmih  = Wc + 4 * 384 * 128;       // 4*384
    int* rowptr  = (int*)(bmih + 4 * 384);   // NN+4 (padded for alignment)
    int* wptr    = rowptr + NN + 4;          // NN
    int* cnt     = wptr + NN;                // NN
    int* bsum    = cnt + NN;                 // 128 (scan block totals)
    int* ssrc    = bsum + 128;               // NE
    unsigned short* wcb  = (unsigned short*)(ssrc + NE); // 4*49152 bf16 frags
    unsigned short* whhb = wcb + 4 * 49152;              // 4*49152 bf16 frags
    unsigned short* nfb  = whhb + 4 * 49152;             // NNP*96 bf16 padded nf
    unsigned short* web  = nfb + (size_t)NNP * 96;       // 12288 emb B-frags

    // ---- once-per-call precompute: weights (+bf16 frags), nf cast, CSR ----
    k_wc<<<4 * 384, 128, 0, stream>>>(Wih, msgW, msgb, Wc, bmih);
    k_frag<<<8 * 192, 256, 0, stream>>>(Wc, Whh, wcb, whhb);
    k_nfb<<<(NN * 24 + 255) / 256, 256, 0, stream>>>(nf, nfb);
    k_wfrag_emb<<<48, 256, 0, stream>>>(embW, web);
    hipMemsetAsync(cnt, 0, NN * sizeof(int), stream);
    k_count<<<(NE + 255) / 256, 256, 0, stream>>>(dst, cnt);
    k_scan1<<<SCAN_G, SCAN_B, 0, stream>>>(cnt, rowptr, bsum);
    k_scan2<<<1, 128, 0, stream>>>(bsum, rowptr);
    k_scan3<<<SCAN_G, SCAN_B, 0, stream>>>(rowptr, bsum, wptr);
    k_scatter<<<(NE + 255) / 256, 256, 0, stream>>>(src, dst, wptr, ssrc);

    // ---- MFMA embedding + BN + att-proj for layer 0 ----
    hipMemsetAsync(bnsum, 0, 256 * sizeof(double), stream);
    k_embed_m<<<NNP / 64, 256, 0, stream>>>(nfb, web, embb, y, bnsum);
    k_bnfin<<<1, 128, 0, stream>>>(bnsum, embg, embbe, ss);
    k_bnx<<<NN / 4, 256, 0, stream>>>(y, ss, attW, x, xb, as_, ad_);

    for (int l = 0; l < NLAYERS; l++) {
        k_gather<<<NN / 8, 256, 0, stream>>>(rowptr, ssrc, xb, as_, ad_, attb, l, aggxb, sumatt);
        hipMemsetAsync(bnsum, 0, 256 * sizeof(double), stream);
        k_gru<<<NNP / 64, 256, 0, stream>>>(
            aggxb, sumatt, xb, x,
            wcb + (size_t)l * 49152, bmih + (size_t)l * 384, bih + (size_t)l * 384,
            whhb + (size_t)l * 49152, bhh + (size_t)l * 384, y, bnsum);
        k_bnfin<<<1, 128, 0, stream>>>(bnsum, bng + (size_t)l * HID, bnb + (size_t)l * HID, ss);
        const float* attW_next = attW + (size_t)((l + 1 < NLAYERS) ? l + 1 : l) * 256;
        k_bnx<<<NN / 4, 256, 0, stream>>>(y, ss, attW_next, x, xb, as_, ad_);
    }

    hipMemsetAsync(gr, 0, NGRAPHS * HID * sizeof(float), stream);
    k_pool<<<(NN + 255) / 256, 256, 0, stream>>>(x, batch, gr);
    k_readout<<<NGRAPHS, 64, 0, stream>>>(gr, roW1, rob1, roW2, rob2, out);
}

// Round 7
// 736.871 us; speedup vs baseline: 8.0626x; 1.0487x over previous
//
#include <hip/hip_runtime.h>
#include <math.h>

#define NN 50000
#define NE 600000
#define ADIM 75
#define HID 128
#define NLAYERS 4
#define NGRAPHS 128
#define BN_EPS 1e-5f
#define NNP 50048   // NN padded to 64-node blocks

typedef short bhalf8 __attribute__((ext_vector_type(8)));
typedef float floatx4 __attribute__((ext_vector_type(4)));

__device__ __forceinline__ float sigm(float v) { return 1.0f / (1.0f + __expf(-v)); }
// fast tanh via exp2-based __expf; saturates correctly at +/-inf
__device__ __forceinline__ float tanh_f(float v) {
    return 1.0f - 2.0f / (__expf(2.0f * v) + 1.0f);
}

// fp32 -> bf16 with round-to-nearest-even
__device__ __forceinline__ unsigned short f2bf(float f) {
    unsigned u = __builtin_bit_cast(unsigned, f);
    u = (u + 0x7FFFu + ((u >> 16) & 1u)) >> 16;
    return (unsigned short)u;
}
__device__ __forceinline__ float bf2f(unsigned short h) {
    return __builtin_bit_cast(float, ((unsigned)h) << 16);
}

// ---------------------------------------------------------------------------
// nf [NN x 75] fp32 -> nfb [NNP x 96] bf16 (K zero-padded 75->96)
// ---------------------------------------------------------------------------
__global__ __launch_bounds__(256) void k_nfb(
    const float* __restrict__ nf, unsigned short* __restrict__ nfb)
{
    int e = blockIdx.x * 256 + threadIdx.x;      // (n, k4): 50000*24
    if (e >= NN * 24) return;
    int n = e / 24, k4 = e - n * 24;
    ushort4 o;
    int k = k4 * 4;
    o.x = (k + 0 < ADIM) ? f2bf(nf[(size_t)n * ADIM + k + 0]) : 0;
    o.y = (k + 1 < ADIM) ? f2bf(nf[(size_t)n * ADIM + k + 1]) : 0;
    o.z = (k + 2 < ADIM) ? f2bf(nf[(size_t)n * ADIM + k + 2]) : 0;
    o.w = (k + 3 < ADIM) ? f2bf(nf[(size_t)n * ADIM + k + 3]) : 0;
    ((ushort4*)nfb)[(size_t)n * 24 + k4] = o;
}

// ---------------------------------------------------------------------------
// embW [128 x 75] -> bf16 B-fragments, K padded to 96:
//   layout [tc(8)][kb(3)][quad(4)][n(16)][j(8)], elem = W[tc*16+n][kb*32+quad*8+j]
// ---------------------------------------------------------------------------
__global__ __launch_bounds__(256) void k_wfrag_emb(
    const float* __restrict__ W, unsigned short* __restrict__ web)
{
    int e = blockIdx.x * 256 + threadIdx.x;      // 0..12287
    int j = e & 7, n = (e >> 3) & 15, quad = (e >> 7) & 3;
    int kb = (e >> 9) % 3, tc = e / 1536;
    int row = tc * 16 + n;
    int kk = kb * 32 + quad * 8 + j;
    web[e] = (kk < ADIM) ? f2bf(W[row * ADIM + kk]) : 0;
}

// ---------------------------------------------------------------------------
// MFMA embedding: y = relu(nf @ embW^T + b), BN sums.
// block 256 = 4 waves x 16 nodes (64 nodes/block); grid 782.
// B-frags read direct global->reg (L2-resident, coalesced 1KB/inst).
// ---------------------------------------------------------------------------
__global__ __launch_bounds__(256) void k_embed_m(
    const unsigned short* __restrict__ nfb, const unsigned short* __restrict__ web,
    const float* __restrict__ b, float* __restrict__ y,
    double* __restrict__ bnsum)
{
    __shared__ __align__(16) float hst[64 * 128];   // 32 KB h staging
    const int t = threadIdx.x;
    const int wave = t >> 6, lane = t & 63;
    const int col = lane & 15, quad = (lane >> 4) & 3;
    const int node0 = blockIdx.x * 64;

    // A-fragments: nfb rows, A[m=col][k=quad*8+j], 3 K-blocks
    const int anode = node0 + wave * 16 + col;
    bhalf8 afN[3];
#pragma unroll
    for (int kb = 0; kb < 3; kb++)
        afN[kb] = *(const bhalf8*)&nfb[(size_t)anode * 96 + kb * 32 + quad * 8];

    floatx4 acc[8];
#pragma unroll
    for (int tc = 0; tc < 8; tc++) {
        float bv = b[tc * 16 + col];
        acc[tc] = (floatx4){bv, bv, bv, bv};
    }

#pragma unroll
    for (int tc = 0; tc < 8; tc++) {
        bhalf8 bfr[3];
#pragma unroll
        for (int kb = 0; kb < 3; kb++)
            bfr[kb] = *(const bhalf8*)&web[((tc * 3 + kb) * 64 + lane) * 8];
#pragma unroll
        for (int kb = 0; kb < 3; kb++)
            acc[tc] = __builtin_amdgcn_mfma_f32_16x16x32_bf16(afN[kb], bfr[kb], acc[tc], 0, 0, 0);
    }

#pragma unroll
    for (int tc = 0; tc < 8; tc++)
#pragma unroll
        for (int e = 0; e < 4; e++) {
            float v = fmaxf(acc[tc][e], 0.0f);
            hst[(wave * 16 + quad * 4 + e) * 128 + tc * 16 + col] = v;
        }
    __syncthreads();

#pragma unroll
    for (int i = 0; i < 32; i++) {
        int idx = t + i * 256;
        if (node0 + (idx >> 7) < NN) y[(size_t)node0 * HID + idx] = hst[idx];
    }
    if (t < 128) {
        int count = NN - node0; if (count > 64) count = 64;
        float s = 0.f, s2 = 0.f;
        for (int m = 0; m < count; m++) { float v = hst[m * 128 + t]; s += v; s2 += v * v; }
        unsafeAtomicAdd(&bnsum[t], (double)s);
        unsafeAtomicAdd(&bnsum[128 + t], (double)s2);
    }
}

// ---------------------------------------------------------------------------
// BN finalize: scale/shift from double sums
// ---------------------------------------------------------------------------
__global__ void k_bnfin(const double* __restrict__ bnsum, const float* __restrict__ g,
                        const float* __restrict__ beta, float* __restrict__ ss)
{
    int f = threadIdx.x;
    double mean = bnsum[f] / (double)NN;
    double var  = bnsum[128 + f] / (double)NN - mean * mean;
    float inv = rsqrtf((float)var + BN_EPS);
    float sc = g[f] * inv;
    ss[f] = sc;
    ss[128 + f] = beta[f] - (float)mean * sc;
}

// ---------------------------------------------------------------------------
// Fused BN-apply + bf16 mirror + attention projections for the NEXT layer
// ---------------------------------------------------------------------------
__global__ __launch_bounds__(256) void k_bnx(
    const float* __restrict__ y, const float* __restrict__ ss,
    const float* __restrict__ attW, float* __restrict__ x,
    unsigned short* __restrict__ xb,
    float* __restrict__ as_, float* __restrict__ ad_)
{
    const int t = threadIdx.x;
    const int n = blockIdx.x * 4 + (t >> 6);
    const int lane = t & 63;
    float2 sc = ((const float2*)ss)[lane];
    float2 sh = ((const float2*)(ss + 128))[lane];
    float2 v = ((const float2*)y)[(size_t)n * 64 + lane];
    float2 xv;
    xv.x = v.x * sc.x + sh.x;
    xv.y = v.y * sc.y + sh.y;
    ((float2*)x)[(size_t)n * 64 + lane] = xv;
    unsigned pk = (unsigned)f2bf(xv.x) | ((unsigned)f2bf(xv.y) << 16);
    ((unsigned*)xb)[(size_t)n * 64 + lane] = pk;
    float2 aws = ((const float2*)attW)[lane];
    float2 awd = ((const float2*)(attW + 128))[lane];
    float pas = xv.x * aws.x + xv.y * aws.y;
    float pad = xv.x * awd.x + xv.y * awd.y;
#pragma unroll
    for (int msk = 32; msk >= 1; msk >>= 1) {
        pas += __shfl_xor(pas, msk);
        pad += __shfl_xor(pad, msk);
    }
    if (lane == 0) { as_[n] = pas; ad_[n] = pad; }
}

// ---------------------------------------------------------------------------
// Combined-weight precompute: Wc[l] = Wih[l] @ Wm[l], bmih[l] = Wih[l] @ bm[l]
// ---------------------------------------------------------------------------
__global__ __launch_bounds__(128) void k_wc(
    const float* __restrict__ Wih, const float* __restrict__ Wm,
    const float* __restrict__ bm, float* __restrict__ Wc, float* __restrict__ bmih)
{
    __shared__ float sw[128];
    __shared__ float red[128];
    const int b = blockIdx.x;
    const int l = b / 384, r = b - l * 384;
    const int t = threadIdx.x;
    const float* wihrow = Wih + ((size_t)l * 384 + r) * 128;
    sw[t] = wihrow[t];
    __syncthreads();
    const float* wm = Wm + (size_t)l * 128 * 128;
    float acc = 0.f;
#pragma unroll 8
    for (int k = 0; k < 128; k++) acc += sw[k] * wm[k * 128 + t];
    Wc[((size_t)l * 384 + r) * 128 + t] = acc;
    red[t] = sw[t] * bm[l * 128 + t];
    __syncthreads();
#pragma unroll
    for (int off = 64; off >= 1; off >>= 1) {
        if (t < off) red[t] += red[t + off];
        __syncthreads();
    }
    if (t == 0) bmih[l * 384 + r] = red[0];
}

// ---------------------------------------------------------------------------
// Convert Wc (fp32) and Whh to bf16 in MFMA B-fragment order:
//   layout [gate(3)][tc(8)][kb(4)][quad(4)][n(16)][j(8)] per layer-matrix
// ---------------------------------------------------------------------------
__global__ __launch_bounds__(256) void k_frag(
    const float* __restrict__ Wc, const float* __restrict__ Whh,
    unsigned short* __restrict__ wcb, unsigned short* __restrict__ whhb)
{
    const int b = blockIdx.x;
    const int mat = b / 192;
    const int e = (b - mat * 192) * 256 + threadIdx.x;   // 0..49151
    const int l = mat >> 1, which = mat & 1;
    const float* src = which ? (Whh + (size_t)l * 49152) : (Wc + (size_t)l * 49152);
    unsigned short* dst = which ? (whhb + (size_t)l * 49152) : (wcb + (size_t)l * 49152);
    int j = e & 7, n = (e >> 3) & 15, quad = (e >> 7) & 3;
    int kb = (e >> 9) & 3, tc = (e >> 11) & 7, g = (e >> 14) & 3;
    int row = g * 128 + tc * 16 + n;
    int kk = kb * 32 + quad * 8 + j;
    dst[e] = f2bf(src[row * 128 + kk]);
}

// ---------------------------------------------------------------------------
// CSR build: histogram, 3-kernel device-wide scan, scatter
// ---------------------------------------------------------------------------
__global__ __launch_bounds__(256) void k_count(const int* __restrict__ dst, int* __restrict__ cnt)
{
    int e = blockIdx.x * 256 + threadIdx.x;
    if (e < NE) atomicAdd(&cnt[dst[e]], 1);
}

#define SCAN_B 512
#define SCAN_G 98          // 98*512 = 50176 >= 50000

__global__ __launch_bounds__(SCAN_B) void k_scan1(
    const int* __restrict__ cnt, int* __restrict__ rowptr, int* __restrict__ bsum)
{
    __shared__ int s[SCAN_B];
    const int t = threadIdx.x;
    const int i = blockIdx.x * SCAN_B + t;
    int v = (i < NN) ? cnt[i] : 0;
    s[t] = v;
    __syncthreads();
#pragma unroll
    for (int off = 1; off < SCAN_B; off <<= 1) {
        int u = (t >= off) ? s[t - off] : 0;
        __syncthreads();
        s[t] += u;
        __syncthreads();
    }
    if (i < NN) rowptr[i] = s[t] - v;        // local exclusive
    if (t == SCAN_B - 1) bsum[blockIdx.x] = s[t];
}

__global__ __launch_bounds__(128) void k_scan2(int* __restrict__ bsum, int* __restrict__ rowptr)
{
    __shared__ int s[128];
    const int t = threadIdx.x;
    int v = (t < SCAN_G) ? bsum[t] : 0;
    s[t] = v;
    __syncthreads();
#pragma unroll
    for (int off = 1; off < 128; off <<= 1) {
        int u = (t >= off) ? s[t - off] : 0;
        __syncthreads();
        s[t] += u;
        __syncthreads();
    }
    if (t < SCAN_G) bsum[t] = s[t] - v;      // exclusive offsets
    if (t == 127) rowptr[NN] = s[127];       // grand total (= NE)
}

__global__ __launch_bounds__(SCAN_B) void k_scan3(
    int* __restrict__ rowptr, const int* __restrict__ bsum, int* __restrict__ wptr)
{
    const int i = blockIdx.x * SCAN_B + threadIdx.x;
    if (i < NN) {
        int v = rowptr[i] + bsum[blockIdx.x];
        rowptr[i] = v;
        wptr[i] = v;
    }
}

__global__ __launch_bounds__(256) void k_scatter(
    const int* __restrict__ src, const int* __restrict__ dst,
    int* __restrict__ wptr, int* __restrict__ ssrc)
{
    int e = blockIdx.x * 256 + threadIdx.x;
    if (e < NE) {
        int d = dst[e];
        int pos = atomicAdd(&wptr[d], 1);
        ssrc[pos] = src[e];
    }
}

// ---------------------------------------------------------------------------
// Gather-aggregate over bf16 x-table (no atomics), software-pipelined
// ---------------------------------------------------------------------------
__global__ __launch_bounds__(256) void k_gather(
    const int* __restrict__ rowptr, const int* __restrict__ ssrc,
    const unsigned short* __restrict__ xb, const float* __restrict__ as_,
    const float* __restrict__ ad_, const float* __restrict__ attb, int l,
    unsigned short* __restrict__ aggxb, float* __restrict__ sumatt)
{
    const int t = threadIdx.x;
    const int n = blockIdx.x * 8 + (t >> 5);
    const int lane = t & 31;
    const int r0 = rowptr[n], r1 = rowptr[n + 1];
    const float adv = ad_[n] + attb[l];
    float4 acc = make_float4(0.f, 0.f, 0.f, 0.f);
    float satt = 0.f;
    if (r0 < r1) {
        int s = ssrc[r0];
        ushort4 v = ((const ushort4*)xb)[(size_t)s * 32 + lane];
        float a = as_[s];
        for (int i = r0; i < r1; i++) {
            int s2 = (i + 1 < r1) ? ssrc[i + 1] : s;
            ushort4 v2 = ((const ushort4*)xb)[(size_t)s2 * 32 + lane];
            float a2 = as_[s2];
            float att = sigm(a + adv);
            acc.x += bf2f(v.x) * att; acc.y += bf2f(v.y) * att;
            acc.z += bf2f(v.z) * att; acc.w += bf2f(v.w) * att;
            satt += att;
            v = v2; a = a2;
        }
    }
    ushort4 o;
    o.x = f2bf(acc.x); o.y = f2bf(acc.y); o.z = f2bf(acc.z); o.w = f2bf(acc.w);
    ((ushort4*)aggxb)[(size_t)n * 32 + lane] = o;
    if (lane == 0) sumatt[n] = satt;
}

// ---------------------------------------------------------------------------
// MFMA GRU, barrier-free K-loop: B-fragments read global->reg (coalesced
// 1KB/inst, L2-resident weights). gi = aggx@Wc^T + sumatt*bmih + bih ;
// gh = x@Whh^T + bhh ; gates; h; BN sums.
// block 256 = 4 waves x 16 nodes (64 nodes/block); grid 782.
// C/D layout: col=lane&15 (output f), row=quad*4+reg (node).
// ---------------------------------------------------------------------------
#define MMG(AF, ACC, BASE)                                                    \
    _Pragma("unroll")                                                         \
    for (int tc = 0; tc < 8; tc++) {                                          \
        bhalf8 bfr[4];                                                        \
        _Pragma("unroll")                                                     \
        for (int kb = 0; kb < 4; kb++)                                        \
            bfr[kb] = *(const bhalf8*)&(BASE)[((tc * 4 + kb) * 64 + lane) * 8]; \
        _Pragma("unroll")                                                     \
        for (int kb = 0; kb < 4; kb++)                                        \
            ACC[tc] = __builtin_amdgcn_mfma_f32_16x16x32_bf16(AF[kb], bfr[kb], ACC[tc], 0, 0, 0); \
    }

__global__ __launch_bounds__(256) void k_gru(
    const unsigned short* __restrict__ aggxb, const float* __restrict__ sumatt,
    const unsigned short* __restrict__ xb,
    const unsigned short* __restrict__ wcb, const float* __restrict__ bmih,
    const float* __restrict__ bih,
    const unsigned short* __restrict__ whhb, const float* __restrict__ bhh,
    float* __restrict__ y, double* __restrict__ bnsum)
{
    __shared__ __align__(16) float hst[64 * 128];   // 32 KB h staging
    const int t = threadIdx.x;
    const int wave = t >> 6, lane = t & 63;
    const int col = lane & 15, quad = (lane >> 4) & 3;
    const int node0 = blockIdx.x * 64;

    // ---- A-fragments: direct bf16 16B loads, A[m=lane&15][k=quad*8+j] ----
    const int anode = node0 + wave * 16 + col;
    bhalf8 afA[4], afX[4];
#pragma unroll
    for (int kb = 0; kb < 4; kb++) {
        afA[kb] = *(const bhalf8*)&aggxb[(size_t)anode * HID + kb * 32 + quad * 8];
        afX[kb] = *(const bhalf8*)&xb[(size_t)anode * HID + kb * 32 + quad * 8];
    }
    float sa[4];
#pragma unroll
    for (int e = 0; e < 4; e++) sa[e] = sumatt[node0 + wave * 16 + quad * 4 + e];

    floatx4 acc_i[8], acc_h[8], gr_[8], gn_[8];

    // ================= gate r (g=0) =================
#pragma unroll
    for (int tc = 0; tc < 8; tc++) {
        int f = 0 * 128 + tc * 16 + col;
        float bi = bih[f], bm = bmih[f], bh = bhh[f];
        acc_i[tc] = (floatx4){bi + sa[0] * bm, bi + sa[1] * bm, bi + sa[2] * bm, bi + sa[3] * bm};
        acc_h[tc] = (floatx4){bh, bh, bh, bh};
    }
    MMG(afA, acc_i, wcb + 0 * 16384);
    MMG(afX, acc_h, whhb + 0 * 16384);
#pragma unroll
    for (int tc = 0; tc < 8; tc++)
#pragma unroll
        for (int e = 0; e < 4; e++)
            gr_[tc][e] = sigm(acc_i[tc][e] + acc_h[tc][e]);

    // ================= gate n (g=2) =================
#pragma unroll
    for (int tc = 0; tc < 8; tc++) {
        int f = 2 * 128 + tc * 16 + col;
        float bi = bih[f], bm = bmih[f], bh = bhh[f];
        acc_i[tc] = (floatx4){bi + sa[0] * bm, bi + sa[1] * bm, bi + sa[2] * bm, bi + sa[3] * bm};
        acc_h[tc] = (floatx4){bh, bh, bh, bh};
    }
    MMG(afA, acc_i, wcb + 2 * 16384);
    MMG(afX, acc_h, whhb + 2 * 16384);
#pragma unroll
    for (int tc = 0; tc < 8; tc++)
#pragma unroll
        for (int e = 0; e < 4; e++)
            gn_[tc][e] = tanh_f(acc_i[tc][e] + gr_[tc][e] * acc_h[tc][e]);

    // ================= gate z (g=1) + h =================
#pragma unroll
    for (int tc = 0; tc < 8; tc++) {
        int f = 1 * 128 + tc * 16 + col;
        float bi = bih[f], bm = bmih[f], bh = bhh[f];
        acc_i[tc] = (floatx4){bi + sa[0] * bm, bi + sa[1] * bm, bi + sa[2] * bm, bi + sa[3] * bm};
        acc_h[tc] = (floatx4){bh, bh, bh, bh};
    }
    MMG(afA, acc_i, wcb + 1 * 16384);
    MMG(afX, acc_h, whhb + 1 * 16384);

#pragma unroll
    for (int tc = 0; tc < 8; tc++) {
#pragma unroll
        for (int e = 0; e < 4; e++) {
            float z = sigm(acc_i[tc][e] + acc_h[tc][e]);
            int nd = node0 + wave * 16 + quad * 4 + e;
            float xv = bf2f(xb[(size_t)nd * HID + tc * 16 + col]);
            float h = (1.0f - z) * gn_[tc][e] + z * xv;
            hst[(wave * 16 + quad * 4 + e) * 128 + tc * 16 + col] = h;
        }
    }
    __syncthreads();

    // coalesced y write
#pragma unroll
    for (int i = 0; i < 32; i++) {
        int idx = t + i * 256;
        if (node0 + (idx >> 7) < NN) y[(size_t)node0 * HID + idx] = hst[idx];
    }
    // BN partial sums
    if (t < 128) {
        int count = NN - node0; if (count > 64) count = 64;
        float s = 0.f, s2 = 0.f;
        for (int m = 0; m < count; m++) { float v = hst[m * 128 + t]; s += v; s2 += v * v; }
        unsafeAtomicAdd(&bnsum[t], (double)s);
        unsafeAtomicAdd(&bnsum[128 + t], (double)s2);
    }
}

// ---------------------------------------------------------------------------
// Segmented sum-pool (batch_idx is SORTED)
// ---------------------------------------------------------------------------
__global__ __launch_bounds__(256) void k_pool(
    const float* __restrict__ x, const int* __restrict__ batch, float* __restrict__ gr)
{
    __shared__ int sb[256];
    const int t = threadIdx.x;
    const int nb = blockIdx.x * 256;
    int ld = nb + t; if (ld >= NN) ld = NN - 1;
    sb[t] = batch[ld];
    __syncthreads();
    const int s = t >> 7, f = t & 127;
    float acc = 0.f; int cur = -1;
    for (int i = s; i < 256; i += 2) {
        int n = nb + i;
        if (n >= NN) break;
        int g = sb[i];
        if (g != cur) {
            if (cur >= 0) unsafeAtomicAdd(&gr[(size_t)cur * HID + f], acc);
            acc = 0.f; cur = g;
        }
        acc += x[(size_t)n * HID + f];
    }
    if (cur >= 0) unsafeAtomicAdd(&gr[(size_t)cur * HID + f], acc);
}

// ---------------------------------------------------------------------------
// Readout: out[g] = relu(gr[g] @ W1^T + b1) @ W2^T + b2   (128 blocks x 64)
// ---------------------------------------------------------------------------
__global__ __launch_bounds__(64) void k_readout(
    const float* __restrict__ gr, const float* __restrict__ W1,
    const float* __restrict__ b1, const float* __restrict__ W2,
    const float* __restrict__ b2, float* __restrict__ out)
{
    const int g = blockIdx.x, j = threadIdx.x;
    float acc = b1[j];
    const float4* grow = (const float4*)&gr[g * HID];
    const float4* wrow = (const float4*)&W1[j * HID];
#pragma unroll
    for (int k4 = 0; k4 < 32; k4++) {
        float4 a = grow[k4], w = wrow[k4];
        acc += a.x * w.x + a.y * w.y + a.z * w.z + a.w * w.w;
    }
    float h = fmaxf(acc, 0.0f) * W2[j];
#pragma unroll
    for (int msk = 32; msk >= 1; msk >>= 1) h += __shfl_xor(h, msk);
    if (j == 0) out[g] = h + b2[0];
}

// ---------------------------------------------------------------------------
extern "C" void kernel_launch(void* const* d_in, const int* in_sizes, int n_in,
                              void* d_out, int out_size, void* d_ws, size_t ws_size,
                              hipStream_t stream)
{
    const float* nf    = (const float*)d_in[0];
    const int*   ei    = (const int*)d_in[1];
    const int*   batch = (const int*)d_in[2];
    const float* embW  = (const float*)d_in[3];
    const float* embb  = (const float*)d_in[4];
    const float* embg  = (const float*)d_in[5];
    const float* embbe = (const float*)d_in[6];
    const float* msgW  = (const float*)d_in[7];
    const float* msgb  = (const float*)d_in[8];
    const float* attW  = (const float*)d_in[9];
    const float* attb  = (const float*)d_in[10];
    const float* Wih   = (const float*)d_in[11];
    const float* bih   = (const float*)d_in[12];
    const float* Whh   = (const float*)d_in[13];
    const float* bhh   = (const float*)d_in[14];
    const float* bng   = (const float*)d_in[15];
    const float* bnb   = (const float*)d_in[16];
    const float* roW1  = (const float*)d_in[17];
    const float* rob1  = (const float*)d_in[18];
    const float* roW2  = (const float*)d_in[19];
    const float* rob2  = (const float*)d_in[20];
    const int* src = ei;
    const int* dst = ei + NE;
    float* out = (float*)d_out;

    // ---- workspace layout (all sections 16B-multiple) ----
    char* base = (char*)d_ws;
    const size_t NH = (size_t)NN * HID;      // 6.4M elements
    double* bnsum = (double*)base;           // 256 doubles = 2048 B
    float* x     = (float*)(base + 2048);    // fp32 node state
    float* y     = x + NH;                   // pre-BN state
    unsigned short* xb    = (unsigned short*)(y + NH);   // bf16 mirror of x
    unsigned short* aggxb = xb + NH;                     // bf16 gather output
    float* as_   = (float*)(aggxb + NH);
    float* ad_   = as_ + NN;
    float* sumatt= ad_ + NN;
    float* ss    = sumatt + NN;              // 256: scale|shift
    float* gr    = ss + 256;                 // 128*128
    float* Wc    = gr + NGRAPHS * HID;       // 4*384*128 fp32
    float* bmih  = Wc + 4 * 384 * 128;       // 4*384
    int* rowptr  = (int*)(bmih + 4 * 384);   // NN+4 (padded for alignment)
    int* wptr    = rowptr + NN + 4;          // NN
    int* cnt     = wptr + NN;                // NN
    int* bsum    = cnt + NN;                 // 128 (scan block totals)
    int* ssrc    = bsum + 128;               // NE
    unsigned short* wcb  = (unsigned short*)(ssrc + NE); // 4*49152 bf16 frags
    unsigned short* whhb = wcb + 4 * 49152;              // 4*49152 bf16 frags
    unsigned short* nfb  = whhb + 4 * 49152;             // NNP*96 bf16 padded nf
    unsigned short* web  = nfb + (size_t)NNP * 96;       // 12288 emb B-frags

    // ---- once-per-call precompute: weights (+bf16 frags), nf cast, CSR ----
    k_wc<<<4 * 384, 128, 0, stream>>>(Wih, msgW, msgb, Wc, bmih);
    k_frag<<<8 * 192, 256, 0, stream>>>(Wc, Whh, wcb, whhb);
    k_nfb<<<(NN * 24 + 255) / 256, 256, 0, stream>>>(nf, nfb);
    k_wfrag_emb<<<48, 256, 0, stream>>>(embW, web);
    hipMemsetAsync(cnt, 0, NN * sizeof(int), stream);
    k_count<<<(NE + 255) / 256, 256, 0, stream>>>(dst, cnt);
    k_scan1<<<SCAN_G, SCAN_B, 0, stream>>>(cnt, rowptr, bsum);
    k_scan2<<<1, 128, 0, stream>>>(bsum, rowptr);
    k_scan3<<<SCAN_G, SCAN_B, 0, stream>>>(rowptr, bsum, wptr);
    k_scatter<<<(NE + 255) / 256, 256, 0, stream>>>(src, dst, wptr, ssrc);

    // ---- MFMA embedding + BN + att-proj for layer 0 ----
    hipMemsetAsync(bnsum, 0, 256 * sizeof(double), stream);
    k_embed_m<<<NNP / 64, 256, 0, stream>>>(nfb, web, embb, y, bnsum);
    k_bnfin<<<1, 128, 0, stream>>>(bnsum, embg, embbe, ss);
    k_bnx<<<NN / 4, 256, 0, stream>>>(y, ss, attW, x, xb, as_, ad_);

    for (int l = 0; l < NLAYERS; l++) {
        k_gather<<<NN / 8, 256, 0, stream>>>(rowptr, ssrc, xb, as_, ad_, attb, l, aggxb, sumatt);
        hipMemsetAsync(bnsum, 0, 256 * sizeof(double), stream);
        k_gru<<<NNP / 64, 256, 0, stream>>>(
            aggxb, sumatt, xb,
            wcb + (size_t)l * 49152, bmih + (size_t)l * 384, bih + (size_t)l * 384,
            whhb + (size_t)l * 49152, bhh + (size_t)l * 384, y, bnsum);
        k_bnfin<<<1, 128, 0, stream>>>(bnsum, bng + (size_t)l * HID, bnb + (size_t)l * HID, ss);
        const float* attW_next = attW + (size_t)((l + 1 < NLAYERS) ? l + 1 : l) * 256;
        k_bnx<<<NN / 4, 256, 0, stream>>>(y, ss, attW_next, x, xb, as_, ad_);
    }

    hipMemsetAsync(gr, 0, NGRAPHS * HID * sizeof(float), stream);
    k_pool<<<(NN + 255) / 256, 256, 0, stream>>>(x, batch, gr);
    k_readout<<<NGRAPHS, 64, 0, stream>>>(gr, roW1, rob1, roW2, rob2, out);
}